// Round 1
// baseline (688.186 us; speedup 1.0000x reference)
//
#include <hip/hip_runtime.h>

#define N_NODES 30000
#define N_EDGES 960000
#define NGRAPH  64
#define BN_EPS  1e-5f

typedef __bf16 bf16x8 __attribute__((ext_vector_type(8)));
typedef float  f32x4  __attribute__((ext_vector_type(4)));

__device__ __forceinline__ unsigned short f2bf(float f) {
  union { float f; unsigned u; } v; v.f = f;
  unsigned r = (v.u + 0x7FFFu + ((v.u >> 16) & 1u)) >> 16;
  return (unsigned short)r;
}
__device__ __forceinline__ float bf2f(unsigned short u) {
  union { unsigned u; float f; } v; v.u = ((unsigned)u) << 16;
  return v.f;
}

// ---------------- casts ----------------
__global__ void cast_x_kernel(const float* __restrict__ x,
                              unsigned short* __restrict__ xh,
                              unsigned short* __restrict__ xl) {
  int i = (blockIdx.x * 256 + threadIdx.x) * 4;
  float4 v = *(const float4*)(x + i);
  ushort4 h, l;
  h.x = f2bf(v.x); l.x = f2bf(v.x - bf2f(h.x));
  h.y = f2bf(v.y); l.y = f2bf(v.y - bf2f(h.y));
  h.z = f2bf(v.z); l.z = f2bf(v.z - bf2f(h.z));
  h.w = f2bf(v.w); l.w = f2bf(v.w - bf2f(h.w));
  *(ushort4*)(xh + i) = h;
  *(ushort4*)(xl + i) = l;
}

// transpose-cast gat_w [448,256] -> wt[n][k], mlp_w [256,128] -> mwt[n][k]
__global__ void cast_w_kernel(const float* __restrict__ gw, const float* __restrict__ mw,
                              unsigned short* __restrict__ wth, unsigned short* __restrict__ wtl,
                              unsigned short* __restrict__ mwth, unsigned short* __restrict__ mwtl) {
  int o = blockIdx.x * 256 + threadIdx.x;
  float v; unsigned short *ph, *pl; int oi;
  if (o < 448 * 256) {
    int n = o / 448, k = o - n * 448;
    v = gw[k * 256 + n]; ph = wth; pl = wtl; oi = o;
  } else {
    int o2 = o - 448 * 256;
    int n = o2 / 256, k = o2 - n * 256;
    v = mw[k * 128 + n]; ph = mwth; pl = mwtl; oi = o2;
  }
  unsigned short h = f2bf(v);
  ph[oi] = h; pl[oi] = f2bf(v - bf2f(h));
}

// ---------------- CSR build ----------------
__global__ void hist_kernel(const int* __restrict__ ei, int* __restrict__ deg) {
  int i = blockIdx.x * 256 + threadIdx.x;
  atomicAdd(&deg[ei[N_EDGES + i]], 1);
}

__global__ void scan_kernel(const int* __restrict__ deg, int* __restrict__ offs,
                            int* __restrict__ cur, int n) {
  __shared__ int sdata[1024];
  __shared__ int running;
  if (threadIdx.x == 0) running = 0;
  __syncthreads();
  for (int base = 0; base < n; base += 1024) {
    int i = base + (int)threadIdx.x;
    int v = (i < n) ? deg[i] : 0;
    sdata[threadIdx.x] = v;
    __syncthreads();
    for (int o = 1; o < 1024; o <<= 1) {
      int t = (threadIdx.x >= (unsigned)o) ? sdata[threadIdx.x - o] : 0;
      __syncthreads();
      sdata[threadIdx.x] += t;
      __syncthreads();
    }
    int excl = sdata[threadIdx.x] - v;
    if (i < n) { int p = running + excl; offs[i] = p; cur[i] = p; }
    __syncthreads();
    if (threadIdx.x == 0) running += sdata[1023];
    __syncthreads();
  }
  if (threadIdx.x == 0) offs[n] = running;
}

__global__ void scatter_kernel(const int* __restrict__ ei, int* __restrict__ cur,
                               int* __restrict__ csr) {
  int i = blockIdx.x * 256 + threadIdx.x;
  int dst = ei[N_EDGES + i], src = ei[i];
  int pos = atomicAdd(&cur[dst], 1);
  csr[pos] = src;
}

// ---------------- split-bf16 MFMA GEMM: wave computes 16x64 tile ----------------
// A: [M,K] bf16 (hi + optional lo), Bt: [N,K] bf16 (hi + lo). Out fp32 or bf16.
__global__ void gemm_bf16_kernel(const unsigned short* __restrict__ Ah,
                                 const unsigned short* __restrict__ Al,
                                 const unsigned short* __restrict__ Bh,
                                 const unsigned short* __restrict__ Bl,
                                 float* __restrict__ Cf, unsigned short* __restrict__ Cbf,
                                 const float* __restrict__ bias,
                                 int K, int nct, int totalWaves) {
  int waveId = blockIdx.x * 4 + ((int)threadIdx.x >> 6);
  if (waveId >= totalWaves) return;
  int rt = waveId / nct, ct = waveId - rt * nct;
  int lane = threadIdx.x & 63;
  int m = lane & 15, quad = lane >> 4;
  size_t arow = (size_t)(rt * 16 + m) * K + quad * 8;
  f32x4 acc[4];
#pragma unroll
  for (int c = 0; c < 4; ++c) acc[c] = (f32x4){0.f, 0.f, 0.f, 0.f};
  for (int k = 0; k < K; k += 32) {
    bf16x8 ah = *(const bf16x8*)(Ah + arow + k);
    bf16x8 al = ah;
    if (Al) al = *(const bf16x8*)(Al + arow + k);
#pragma unroll
    for (int c = 0; c < 4; ++c) {
      size_t bofs = (size_t)(ct * 64 + c * 16 + m) * K + k + quad * 8;
      bf16x8 bh = *(const bf16x8*)(Bh + bofs);
      bf16x8 bl = *(const bf16x8*)(Bl + bofs);
      acc[c] = __builtin_amdgcn_mfma_f32_16x16x32_bf16(ah, bh, acc[c], 0, 0, 0);
      acc[c] = __builtin_amdgcn_mfma_f32_16x16x32_bf16(ah, bl, acc[c], 0, 0, 0);
      if (Al) acc[c] = __builtin_amdgcn_mfma_f32_16x16x32_bf16(al, bh, acc[c], 0, 0, 0);
    }
  }
  int N = nct * 64;
#pragma unroll
  for (int c = 0; c < 4; ++c) {
    int col = ct * 64 + c * 16 + m;
    float bv = bias ? bias[col] : 0.f;
#pragma unroll
    for (int r = 0; r < 4; ++r) {
      int row = rt * 16 + quad * 4 + r;
      float v = acc[c][r] + bv;
      if (Cf) Cf[(size_t)row * N + col] = v;
      else    Cbf[(size_t)row * N + col] = f2bf(v);
    }
  }
}

// ---------------- a_s / a_d: one wave per node ----------------
__global__ void asad_kernel(const unsigned short* __restrict__ xp,
                            const float* __restrict__ asrc, const float* __restrict__ adst,
                            float* __restrict__ a_s, float* __restrict__ a_d) {
  int nid = (blockIdx.x * 256 + (int)threadIdx.x) >> 6;
  int lane = threadIdx.x & 63;
  int head = lane >> 5;
  ushort4 u = *(const ushort4*)(xp + (size_t)nid * 256 + lane * 4);
  float vx = bf2f(u.x), vy = bf2f(u.y), vz = bf2f(u.z), vw = bf2f(u.w);
  int ci = head * 128 + (lane & 31) * 4;
  float4 s4 = *(const float4*)(asrc + ci);
  float4 d4 = *(const float4*)(adst + ci);
  float ps = vx * s4.x + vy * s4.y + vz * s4.z + vw * s4.w;
  float pd = vx * d4.x + vy * d4.y + vz * d4.z + vw * d4.w;
#pragma unroll
  for (int o = 16; o; o >>= 1) { ps += __shfl_xor(ps, o); pd += __shfl_xor(pd, o); }
  if ((lane & 31) == 0) {
    a_s[2 * nid + head] = ps;
    a_d[2 * nid + head] = pd;
  }
}

// ---------------- attention: one wave per dst node ----------------
__global__ void attn_kernel(const unsigned short* __restrict__ xp,
                            const float* __restrict__ a_s, const float* __restrict__ a_d,
                            const int* __restrict__ offs, const int* __restrict__ csr,
                            const float* __restrict__ bias, unsigned short* __restrict__ y) {
  int nid = (blockIdx.x * 256 + (int)threadIdx.x) >> 6;
  int lane = threadIdx.x & 63;
  float d0 = a_d[2 * nid], d1 = a_d[2 * nid + 1];
  float s0 = a_s[2 * nid], s1 = a_s[2 * nid + 1];
  int beg = offs[nid], end = offs[nid + 1];
  float e0s = s0 + d0; e0s = e0s > 0.f ? e0s : 0.2f * e0s;
  float e1s = s1 + d1; e1s = e1s > 0.f ? e1s : 0.2f * e1s;
  float m0 = e0s, m1 = e1s;
  for (int j = beg + lane; j < end; j += 64) {
    int s = csr[j];
    float as0 = a_s[2 * s], as1 = a_s[2 * s + 1];
    float e0 = as0 + d0; e0 = e0 > 0.f ? e0 : 0.2f * e0;
    float e1 = as1 + d1; e1 = e1 > 0.f ? e1 : 0.2f * e1;
    m0 = fmaxf(m0, e0); m1 = fmaxf(m1, e1);
  }
#pragma unroll
  for (int o = 32; o; o >>= 1) {
    m0 = fmaxf(m0, __shfl_xor(m0, o));
    m1 = fmaxf(m1, __shfl_xor(m1, o));
  }
  int head = lane >> 5;
  float dh = head ? d1 : d0;
  float mh = head ? m1 : m0;
  float ax = 0.f, ay = 0.f, az = 0.f, aw = 0.f, wsum = 0.f;
  { // self loop
    float e = head ? e1s : e0s;
    float w = __expf(e - mh);
    ushort4 u = *(const ushort4*)(xp + (size_t)nid * 256 + lane * 4);
    ax += w * bf2f(u.x); ay += w * bf2f(u.y); az += w * bf2f(u.z); aw += w * bf2f(u.w);
    wsum += w;
  }
  for (int j = beg; j < end; ++j) {
    int s = csr[j];
    float as = a_s[2 * s + head];
    float e = as + dh; e = e > 0.f ? e : 0.2f * e;
    float w = __expf(e - mh);
    ushort4 u = *(const ushort4*)(xp + (size_t)s * 256 + lane * 4);
    ax += w * bf2f(u.x); ay += w * bf2f(u.y); az += w * bf2f(u.z); aw += w * bf2f(u.w);
    wsum += w;
  }
  float inv = 1.f / wsum;
  float4 b4 = *(const float4*)(bias + lane * 4);
  float o0 = ax * inv + b4.x, o1 = ay * inv + b4.y;
  float o2 = az * inv + b4.z, o3 = aw * inv + b4.w;
  o0 = o0 > 0.f ? o0 : __expf(o0) - 1.f;
  o1 = o1 > 0.f ? o1 : __expf(o1) - 1.f;
  o2 = o2 > 0.f ? o2 : __expf(o2) - 1.f;
  o3 = o3 > 0.f ? o3 : __expf(o3) - 1.f;
  ushort4 yo; yo.x = f2bf(o0); yo.y = f2bf(o1); yo.z = f2bf(o2); yo.w = f2bf(o3);
  *(ushort4*)(y + (size_t)nid * 256 + lane * 4) = yo;
}

// ---------------- per-graph sums + column sumsq (for fused BN0 + pool) ----------------
__global__ void pool_kernel(const float* __restrict__ t, const int* __restrict__ batch,
                            float* __restrict__ S, float* __restrict__ Q,
                            int* __restrict__ cnt, int n) {
  int c = threadIdx.x;            // 128 columns
  int r0 = blockIdx.x * 128;
  int r1 = min(r0 + 128, n);
  float acc = 0.f, q = 0.f;
  int gcur = batch[r0];
  for (int r = r0; r < r1; ++r) {
    int g = batch[r];
    if (g != gcur) { atomicAdd(&S[gcur * 128 + c], acc); acc = 0.f; gcur = g; }
    float v = t[(size_t)r * 128 + c];
    acc += v; q += v * v;
  }
  atomicAdd(&S[gcur * 128 + c], acc);
  atomicAdd(&Q[c], q);
  if (c == 0) {
    int g2 = batch[r0]; int k = 0;
    for (int r = r0; r < r1; ++r) {
      int g = batch[r];
      if (g != g2) { atomicAdd(&cnt[g2], k); k = 0; g2 = g; }
      k++;
    }
    atomicAdd(&cnt[g2], k);
  }
}

// hp[g][c] = bn0_g*rsq*(S - cnt*mu) + cnt*bn0_b
__global__ void bn0hp_kernel(const float* __restrict__ S, const float* __restrict__ Q,
                             const int* __restrict__ cnt, const float* __restrict__ g0,
                             const float* __restrict__ b0, float* __restrict__ hp) {
  int c = threadIdx.x;            // 128
  float sum = 0.f;
  for (int g = 0; g < NGRAPH; ++g) sum += S[g * 128 + c];
  float mu = sum / (float)N_NODES;
  float var = Q[c] / (float)N_NODES - mu * mu;
  float gam = g0[c] * rsqrtf(var + BN_EPS);
  float bet = b0[c];
  for (int g = 0; g < NGRAPH; ++g) {
    float k = (float)cnt[g];
    hp[g * 128 + c] = gam * (S[g * 128 + c] - k * mu) + k * bet;
  }
}

// ---------------- FC head: wave = one output column, 64 lanes = 64 rows ----------------
__global__ void fc1_kernel(const float* __restrict__ hp, const float* __restrict__ w,
                           const float* __restrict__ b, const float* __restrict__ bng,
                           const float* __restrict__ bnb, float* __restrict__ z1) {
  int wv = threadIdx.x >> 6, lane = threadIdx.x & 63;
  int j = blockIdx.x * 4 + wv;    // 0..511
  float acc = b[j];
  for (int c = 0; c < 128; ++c) acc += hp[lane * 128 + c] * w[c * 512 + j];
  float s1 = acc, s2 = acc * acc;
#pragma unroll
  for (int o = 32; o; o >>= 1) { s1 += __shfl_xor(s1, o); s2 += __shfl_xor(s2, o); }
  float mu = s1 * (1.f / 64.f), var = s2 * (1.f / 64.f) - mu * mu;
  float z = bng[j] * (acc - mu) * rsqrtf(var + BN_EPS) + bnb[j];
  z1[lane * 512 + j] = fmaxf(z, 0.f);
}

__global__ void fc2_kernel(const float* __restrict__ z1, const float* __restrict__ w,
                           const float* __restrict__ b, const float* __restrict__ bng,
                           const float* __restrict__ bnb, float* __restrict__ z2) {
  int wv = threadIdx.x >> 6, lane = threadIdx.x & 63;
  int j = blockIdx.x * 4 + wv;    // 0..255
  float acc = b[j];
  for (int c = 0; c < 512; ++c) acc += z1[lane * 512 + c] * w[c * 256 + j];
  float s1 = acc, s2 = acc * acc;
#pragma unroll
  for (int o = 32; o; o >>= 1) { s1 += __shfl_xor(s1, o); s2 += __shfl_xor(s2, o); }
  float mu = s1 * (1.f / 64.f), var = s2 * (1.f / 64.f) - mu * mu;
  float z = bng[j] * (acc - mu) * rsqrtf(var + BN_EPS) + bnb[j];
  z2[lane * 256 + j] = fmaxf(z, 0.f);
}

__global__ void fc3_kernel(const float* __restrict__ z2, const float* __restrict__ w,
                           const float* __restrict__ b, const float* __restrict__ bng,
                           const float* __restrict__ bnb, float* __restrict__ out) {
  int lane = threadIdx.x;         // 64
  float acc = b[0];
  for (int c = 0; c < 256; ++c) acc += z2[lane * 256 + c] * w[c];
  float s1 = acc, s2 = acc * acc;
#pragma unroll
  for (int o = 32; o; o >>= 1) { s1 += __shfl_xor(s1, o); s2 += __shfl_xor(s2, o); }
  float mu = s1 * (1.f / 64.f), var = s2 * (1.f / 64.f) - mu * mu;
  out[lane] = bng[0] * (acc - mu) * rsqrtf(var + BN_EPS) + bnb[0];
}

extern "C" void kernel_launch(void* const* d_in, const int* in_sizes, int n_in,
                              void* d_out, int out_size, void* d_ws, size_t ws_size,
                              hipStream_t stream) {
  const float* x     = (const float*)d_in[0];
  const float* gat_w = (const float*)d_in[1];
  const float* a_src = (const float*)d_in[2];
  const float* a_dst = (const float*)d_in[3];
  const float* gbias = (const float*)d_in[4];
  const float* mlp_w = (const float*)d_in[5];
  const float* mlp_b = (const float*)d_in[6];
  const float* bn0g  = (const float*)d_in[7];
  const float* bn0b  = (const float*)d_in[8];
  const float* fc1w  = (const float*)d_in[9];
  const float* fc1b  = (const float*)d_in[10];
  const float* bn1g  = (const float*)d_in[11];
  const float* bn1b  = (const float*)d_in[12];
  const float* fc2w  = (const float*)d_in[13];
  const float* fc2b  = (const float*)d_in[14];
  const float* bn2g  = (const float*)d_in[15];
  const float* bn2b  = (const float*)d_in[16];
  const float* fc3w  = (const float*)d_in[17];
  const float* fc3b  = (const float*)d_in[18];
  const float* bn3g  = (const float*)d_in[19];
  const float* bn3b  = (const float*)d_in[20];
  const int* eidx    = (const int*)d_in[21];
  const int* batch   = (const int*)d_in[22];
  float* out = (float*)d_out;

  char* base = (char*)d_ws;
  size_t off = 0;
  auto take = [&](size_t bytes) -> char* {
    char* p = base + off;
    off += (bytes + 255) & ~(size_t)255;
    return p;
  };
  unsigned short* xp   = (unsigned short*)take((size_t)N_NODES * 256 * 2); // bf16 xp
  unsigned short* xbfh = (unsigned short*)take((size_t)N_NODES * 448 * 2);
  unsigned short* xbfl = (unsigned short*)take((size_t)N_NODES * 448 * 2);
  unsigned short* wth  = (unsigned short*)take(448 * 256 * 2);
  unsigned short* wtl  = (unsigned short*)take(448 * 256 * 2);
  unsigned short* mwth = (unsigned short*)take(128 * 256 * 2);
  unsigned short* mwtl = (unsigned short*)take(128 * 256 * 2);
  float* a_s = (float*)take((size_t)N_NODES * 2 * 4);
  float* a_d = (float*)take((size_t)N_NODES * 2 * 4);
  int* deg   = (int*)take((size_t)N_NODES * 4);
  int* offs  = (int*)take((size_t)(N_NODES + 1) * 4);
  int* cur   = (int*)take((size_t)N_NODES * 4);
  int* csr   = (int*)take((size_t)N_EDGES * 4);
  float* S   = (float*)take(NGRAPH * 128 * 4);   // contiguous with Q, cnt (sizes 256-mult)
  float* Q   = (float*)take(128 * 4);
  int* cnt   = (int*)take(NGRAPH * 4);
  float* hp  = (float*)take(NGRAPH * 128 * 4);
  float* z1  = (float*)take(NGRAPH * 512 * 4);
  float* z2  = (float*)take(NGRAPH * 256 * 4);
  // overlays (stream-ordered lifetime): y bf16 over xbfh (dead after gemm1);
  // t fp32 [N,128] over xp (dead after attn). Both 15.36 MB, fit exactly.
  unsigned short* ybf = xbfh;
  float* t = (float*)xp;

  hipMemsetAsync(deg, 0, (size_t)N_NODES * 4, stream);
  hipMemsetAsync(S, 0, (size_t)(NGRAPH * 128 * 4 + 512 + 256), stream);

  cast_x_kernel<<<13125, 256, 0, stream>>>(x, xbfh, xbfl);
  cast_w_kernel<<<576, 256, 0, stream>>>(gat_w, mlp_w, wth, wtl, mwth, mwtl);
  hist_kernel<<<3750, 256, 0, stream>>>(eidx, deg);
  scan_kernel<<<1, 1024, 0, stream>>>(deg, offs, cur, N_NODES);
  scatter_kernel<<<3750, 256, 0, stream>>>(eidx, cur, csr);
  // GEMM1: xp = x @ gat_w  (split-bf16, out bf16), 1875 row-tiles x 4 col-tiles
  gemm_bf16_kernel<<<1875, 256, 0, stream>>>(xbfh, xbfl, wth, wtl,
                                             nullptr, xp, nullptr, 448, 4, 7500);
  asad_kernel<<<7500, 256, 0, stream>>>(xp, a_src, a_dst, a_s, a_d);
  attn_kernel<<<7500, 256, 0, stream>>>(xp, a_s, a_d, offs, csr, gbias, ybf);
  // GEMM2: t = y @ mlp_w + mlp_b  (y single bf16, w split), out fp32
  gemm_bf16_kernel<<<938, 256, 0, stream>>>(ybf, nullptr, mwth, mwtl,
                                            t, nullptr, mlp_b, 256, 2, 3750);
  pool_kernel<<<235, 128, 0, stream>>>(t, batch, S, Q, cnt, N_NODES);
  bn0hp_kernel<<<1, 128, 0, stream>>>(S, Q, cnt, bn0g, bn0b, hp);
  fc1_kernel<<<128, 256, 0, stream>>>(hp, fc1w, fc1b, bn1g, bn1b, z1);
  fc2_kernel<<<64, 256, 0, stream>>>(z1, fc2w, fc2b, bn2g, bn2b, z2);
  fc3_kernel<<<1, 64, 0, stream>>>(z2, fc3w, fc3b, bn3g, bn3b, out);

  (void)in_sizes; (void)n_in; (void)out_size; (void)ws_size; (void)bn3g; (void)bn3b;
}

// Round 2
// 656.538 us; speedup vs baseline: 1.0482x; 1.0482x over previous
//
#include <hip/hip_runtime.h>

#define N_NODES 30000
#define N_EDGES 960000
#define NGRAPH  64
#define BN_EPS  1e-5f
#define NB_GEMM 469   // ceil(30000/64)

typedef __bf16 bf16x8 __attribute__((ext_vector_type(8)));
typedef float  f32x4  __attribute__((ext_vector_type(4)));
typedef unsigned short u16x8v __attribute__((ext_vector_type(8)));

__device__ __forceinline__ unsigned short f2bf(float f) {
  union { float f; unsigned u; } v; v.f = f;
  unsigned r = (v.u + 0x7FFFu + ((v.u >> 16) & 1u)) >> 16;
  return (unsigned short)r;
}
__device__ __forceinline__ float bf2f(unsigned short u) {
  union { unsigned u; float f; } v; v.u = ((unsigned)u) << 16;
  return v.f;
}
__device__ __forceinline__ void gld_lds16(const void* g, void* l) {
  __builtin_amdgcn_global_load_lds(
      (const __attribute__((address_space(1))) unsigned int*)g,
      (__attribute__((address_space(3))) unsigned int*)l, 16, 0, 0);
}

// transpose-cast gat_w [448,256] -> wt[n][k] hi/lo, mlp_w [256,128] -> mwt[n][k] hi/lo
__global__ void cast_w_kernel(const float* __restrict__ gw, const float* __restrict__ mw,
                              unsigned short* __restrict__ wth, unsigned short* __restrict__ wtl,
                              unsigned short* __restrict__ mwth, unsigned short* __restrict__ mwtl) {
  int o = blockIdx.x * 256 + threadIdx.x;
  float v; unsigned short *ph, *pl; int oi;
  if (o < 448 * 256) {
    int n = o / 448, k = o - n * 448;
    v = gw[k * 256 + n]; ph = wth; pl = wtl; oi = o;
  } else {
    int o2 = o - 448 * 256;
    int n = o2 / 256, k = o2 - n * 256;
    v = mw[k * 128 + n]; ph = mwth; pl = mwtl; oi = o2;
  }
  unsigned short h = f2bf(v);
  ph[oi] = h; pl[oi] = f2bf(v - bf2f(h));
}

// ---------------- CSR build ----------------
__global__ void hist_kernel(const int* __restrict__ ei, int* __restrict__ deg) {
  int i = blockIdx.x * 256 + threadIdx.x;
  atomicAdd(&deg[ei[N_EDGES + i]], 1);
}

__global__ void scan_kernel(const int* __restrict__ deg, int* __restrict__ offs,
                            int* __restrict__ cur, int n) {
  __shared__ int wsum[16];
  __shared__ int wpre[16];
  __shared__ int running;
  int tid = threadIdx.x, widx = tid >> 6, lane = tid & 63;
  if (tid == 0) running = 0;
  __syncthreads();
  for (int base = 0; base < n; base += 1024) {
    int i = base + tid;
    int v = (i < n) ? deg[i] : 0;
    int s = v;
#pragma unroll
    for (int o = 1; o <= 32; o <<= 1) {
      int t = __shfl_up(s, o, 64);
      if (lane >= o) s += t;
    }
    if (lane == 63) wsum[widx] = s;
    __syncthreads();
    if (tid == 0) {
      int acc = 0;
#pragma unroll
      for (int j = 0; j < 16; ++j) { wpre[j] = acc; acc += wsum[j]; }
    }
    __syncthreads();
    int excl = running + wpre[widx] + (s - v);
    if (i < n) { offs[i] = excl; cur[i] = excl; }
    __syncthreads();
    if (tid == 0) running += wpre[15] + wsum[15];
    __syncthreads();
  }
  if (threadIdx.x == 0) offs[n] = running;
}

__global__ void scatter_kernel(const int* __restrict__ ei, int* __restrict__ cur,
                               int* __restrict__ csr) {
  int i = blockIdx.x * 256 + threadIdx.x;
  int dst = ei[N_EDGES + i], src = ei[i];
  int pos = atomicAdd(&cur[dst], 1);
  csr[pos] = src;
}

// ---------------- GEMM1 fused: cast(x) -> xp = x@gat_w (split bf16) -> xp bf16 + a_s/a_d ----------------
// Block: 64 rows x 256 cols, 256 threads = 4 waves, wave w = rows [w*16, w*16+16).
// LDS layout [q][row][8] so each 16-lane frag read is 256B contiguous (conflict-free).
__global__ void __launch_bounds__(256) gat_gemm_kernel(
    const float* __restrict__ x,
    const unsigned short* __restrict__ wth, const unsigned short* __restrict__ wtl,
    const float* __restrict__ asrc, const float* __restrict__ adst,
    unsigned short* __restrict__ xp, float* __restrict__ a_s, float* __restrict__ a_d) {
  __shared__ unsigned short Ah[4 * 64 * 8], Al[4 * 64 * 8];      // 4KB + 4KB
  __shared__ unsigned short Bh[4 * 256 * 8], Bl[4 * 256 * 8];    // 16KB + 16KB
  int tid = threadIdx.x;
  int w = tid >> 6, lane = tid & 63;
  int m = lane & 15, quad = lane >> 4;
  int r0 = blockIdx.x * 64;
  // A staging role: q = w, row = lane
  int arow_g = r0 + lane;
  bool avalid = arow_g < N_NODES;
  const float* axp = x + (size_t)(avalid ? arow_g : 0) * 448 + w * 8;

  f32x4 acc[16];
#pragma unroll
  for (int c = 0; c < 16; ++c) acc[c] = (f32x4){0.f, 0.f, 0.f, 0.f};

  for (int kc = 0; kc < 14; ++kc) {
    int k0 = kc * 32;
    // ---- stage A (fp32 -> bf16 hi/lo) ----
    float4 v0 = {0.f, 0.f, 0.f, 0.f}, v1 = {0.f, 0.f, 0.f, 0.f};
    if (avalid) {
      v0 = *(const float4*)(axp + k0);
      v1 = *(const float4*)(axp + k0 + 4);
    }
    float vv[8] = {v0.x, v0.y, v0.z, v0.w, v1.x, v1.y, v1.z, v1.w};
    u16x8v hv, lv;
#pragma unroll
    for (int j = 0; j < 8; ++j) {
      unsigned short h = f2bf(vv[j]);
      hv[j] = h;
      lv[j] = f2bf(vv[j] - bf2f(h));
    }
    *(u16x8v*)(Ah + w * 512 + lane * 8) = hv;
    *(u16x8v*)(Al + w * 512 + lane * 8) = lv;
    // ---- stage B via global_load_lds (wave w handles q=w; 4 issues x 64 rows) ----
#pragma unroll
    for (int i = 0; i < 4; ++i) {
      int n = i * 64 + lane;
      gld_lds16(wth + (size_t)n * 448 + k0 + w * 8, Bh + w * 2048 + i * 512);
      gld_lds16(wtl + (size_t)n * 448 + k0 + w * 8, Bl + w * 2048 + i * 512);
    }
    __syncthreads();
    // ---- compute ----
    bf16x8 ah = *(const bf16x8*)(Ah + quad * 512 + (w * 16 + m) * 8);
    bf16x8 al = *(const bf16x8*)(Al + quad * 512 + (w * 16 + m) * 8);
#pragma unroll
    for (int c = 0; c < 16; ++c) {
      bf16x8 bh = *(const bf16x8*)(Bh + quad * 2048 + (c * 16 + m) * 8);
      bf16x8 bl = *(const bf16x8*)(Bl + quad * 2048 + (c * 16 + m) * 8);
      acc[c] = __builtin_amdgcn_mfma_f32_16x16x32_bf16(ah, bh, acc[c], 0, 0, 0);
      acc[c] = __builtin_amdgcn_mfma_f32_16x16x32_bf16(ah, bl, acc[c], 0, 0, 0);
      acc[c] = __builtin_amdgcn_mfma_f32_16x16x32_bf16(al, bh, acc[c], 0, 0, 0);
    }
    __syncthreads();
  }
  // ---- epilogue: a_s/a_d from fp32 accs + xp bf16 store ----
  float ps0[4] = {0, 0, 0, 0}, ps1[4] = {0, 0, 0, 0};
  float pd0[4] = {0, 0, 0, 0}, pd1[4] = {0, 0, 0, 0};
#pragma unroll
  for (int c = 0; c < 16; ++c) {
    int col = c * 16 + m;
    float sa = asrc[col], da = adst[col];
#pragma unroll
    for (int r = 0; r < 4; ++r) {
      float v = acc[c][r];
      if (c < 8) { ps0[r] += v * sa; pd0[r] += v * da; }
      else       { ps1[r] += v * sa; pd1[r] += v * da; }
    }
  }
#pragma unroll
  for (int o = 1; o <= 8; o <<= 1) {
#pragma unroll
    for (int r = 0; r < 4; ++r) {
      ps0[r] += __shfl_xor(ps0[r], o);
      ps1[r] += __shfl_xor(ps1[r], o);
      pd0[r] += __shfl_xor(pd0[r], o);
      pd1[r] += __shfl_xor(pd1[r], o);
    }
  }
  int rowb = r0 + w * 16 + quad * 4;
  if (m == 0) {
#pragma unroll
    for (int r = 0; r < 4; ++r) {
      int row = rowb + r;
      if (row < N_NODES) {
        a_s[2 * row] = ps0[r]; a_s[2 * row + 1] = ps1[r];
        a_d[2 * row] = pd0[r]; a_d[2 * row + 1] = pd1[r];
      }
    }
  }
#pragma unroll
  for (int r = 0; r < 4; ++r) {
    int row = rowb + r;
    if (row < N_NODES) {
#pragma unroll
      for (int c = 0; c < 16; ++c)
        xp[(size_t)row * 256 + c * 16 + m] = f2bf(acc[c][r]);
    }
  }
}

// ---------------- attention: one wave per dst node ----------------
__global__ void attn_kernel(const unsigned short* __restrict__ xp,
                            const float* __restrict__ a_s, const float* __restrict__ a_d,
                            const int* __restrict__ offs, const int* __restrict__ csr,
                            const float* __restrict__ bias, unsigned short* __restrict__ y) {
  int nid = (blockIdx.x * 256 + (int)threadIdx.x) >> 6;
  int lane = threadIdx.x & 63;
  float d0 = a_d[2 * nid], d1 = a_d[2 * nid + 1];
  float s0 = a_s[2 * nid], s1 = a_s[2 * nid + 1];
  int beg = offs[nid], end = offs[nid + 1];
  float e0s = s0 + d0; e0s = e0s > 0.f ? e0s : 0.2f * e0s;
  float e1s = s1 + d1; e1s = e1s > 0.f ? e1s : 0.2f * e1s;
  float m0 = e0s, m1 = e1s;
  for (int j = beg + lane; j < end; j += 64) {
    int s = csr[j];
    float as0 = a_s[2 * s], as1 = a_s[2 * s + 1];
    float e0 = as0 + d0; e0 = e0 > 0.f ? e0 : 0.2f * e0;
    float e1 = as1 + d1; e1 = e1 > 0.f ? e1 : 0.2f * e1;
    m0 = fmaxf(m0, e0); m1 = fmaxf(m1, e1);
  }
#pragma unroll
  for (int o = 32; o; o >>= 1) {
    m0 = fmaxf(m0, __shfl_xor(m0, o));
    m1 = fmaxf(m1, __shfl_xor(m1, o));
  }
  int head = lane >> 5;
  float dh = head ? d1 : d0;
  float mh = head ? m1 : m0;
  float ax = 0.f, ay = 0.f, az = 0.f, aw = 0.f, wsum = 0.f;
  { // self loop
    float e = head ? e1s : e0s;
    float wgt = __expf(e - mh);
    ushort4 u = *(const ushort4*)(xp + (size_t)nid * 256 + lane * 4);
    ax += wgt * bf2f(u.x); ay += wgt * bf2f(u.y); az += wgt * bf2f(u.z); aw += wgt * bf2f(u.w);
    wsum += wgt;
  }
  for (int j = beg; j < end; ++j) {
    int s = csr[j];
    float as = a_s[2 * s + head];
    float e = as + dh; e = e > 0.f ? e : 0.2f * e;
    float wgt = __expf(e - mh);
    ushort4 u = *(const ushort4*)(xp + (size_t)s * 256 + lane * 4);
    ax += wgt * bf2f(u.x); ay += wgt * bf2f(u.y); az += wgt * bf2f(u.z); aw += wgt * bf2f(u.w);
    wsum += wgt;
  }
  float inv = 1.f / wsum;
  float4 b4 = *(const float4*)(bias + lane * 4);
  float o0 = ax * inv + b4.x, o1 = ay * inv + b4.y;
  float o2 = az * inv + b4.z, o3 = aw * inv + b4.w;
  o0 = o0 > 0.f ? o0 : __expf(o0) - 1.f;
  o1 = o1 > 0.f ? o1 : __expf(o1) - 1.f;
  o2 = o2 > 0.f ? o2 : __expf(o2) - 1.f;
  o3 = o3 > 0.f ? o3 : __expf(o3) - 1.f;
  ushort4 yo; yo.x = f2bf(o0); yo.y = f2bf(o1); yo.z = f2bf(o2); yo.w = f2bf(o3);
  *(ushort4*)(y + (size_t)nid * 256 + lane * 4) = yo;
}

// ---------------- GEMM2 fused: t = y@mlp_w + b, pooled into S[g][c], Q[c] (t never stored) ----
__global__ void __launch_bounds__(256) mlp_gemm_kernel(
    const unsigned short* __restrict__ y,
    const unsigned short* __restrict__ mwth, const unsigned short* __restrict__ mwtl,
    const float* __restrict__ mlp_b, const int* __restrict__ batch,
    float* __restrict__ S, float* __restrict__ Q) {
  __shared__ unsigned short Ahs[4 * 64 * 8];                     // 4KB (y is bf16)
  __shared__ unsigned short Bh[4 * 128 * 8], Bl[4 * 128 * 8];    // 8KB + 8KB
  __shared__ float Sloc[128], Qloc[128];
  int tid = threadIdx.x;
  int w = tid >> 6, lane = tid & 63;
  int m = lane & 15, quad = lane >> 4;
  int r0 = blockIdx.x * 64;
  if (tid < 128) { Sloc[tid] = 0.f; Qloc[tid] = 0.f; }

  f32x4 acc[8];
#pragma unroll
  for (int c = 0; c < 8; ++c) acc[c] = (f32x4){0.f, 0.f, 0.f, 0.f};

  for (int kc = 0; kc < 8; ++kc) {
    int k0 = kc * 32;
    // A: wave w stages q=w, rows = lane (y padded to 30016 rows, OOB rows discarded later)
    gld_lds16(y + (size_t)(r0 + lane) * 256 + k0 + w * 8, Ahs + w * 512);
    // B: wave w stages q=w, 2 issues x 64 rows, hi+lo
#pragma unroll
    for (int i = 0; i < 2; ++i) {
      int n = i * 64 + lane;
      gld_lds16(mwth + (size_t)n * 256 + k0 + w * 8, Bh + w * 1024 + i * 512);
      gld_lds16(mwtl + (size_t)n * 256 + k0 + w * 8, Bl + w * 1024 + i * 512);
    }
    __syncthreads();
    bf16x8 ah = *(const bf16x8*)(Ahs + quad * 512 + (w * 16 + m) * 8);
#pragma unroll
    for (int c = 0; c < 8; ++c) {
      bf16x8 bh = *(const bf16x8*)(Bh + quad * 1024 + (c * 16 + m) * 8);
      bf16x8 bl = *(const bf16x8*)(Bl + quad * 1024 + (c * 16 + m) * 8);
      acc[c] = __builtin_amdgcn_mfma_f32_16x16x32_bf16(ah, bh, acc[c], 0, 0, 0);
      acc[c] = __builtin_amdgcn_mfma_f32_16x16x32_bf16(ah, bl, acc[c], 0, 0, 0);
    }
    __syncthreads();
  }
  // ---- fused pool epilogue ----
  int rowb = r0 + w * 16 + quad * 4;
  int gfirst = batch[r0];
  int glast = batch[min(r0 + 63, N_NODES - 1)];
  bool uni = (gfirst == glast);
  bool valid[4]; int gg[4];
#pragma unroll
  for (int r = 0; r < 4; ++r) {
    int row = rowb + r;
    valid[r] = row < N_NODES;
    gg[r] = (!uni && valid[r]) ? batch[row] : gfirst;
  }
#pragma unroll
  for (int c = 0; c < 8; ++c) {
    int col = c * 16 + m;
    float bv = mlp_b[col];
    float sc = 0.f, qc = 0.f;
#pragma unroll
    for (int r = 0; r < 4; ++r) {
      if (valid[r]) {
        float v = acc[c][r] + bv;
        qc += v * v;
        if (uni) sc += v;
        else atomicAdd(&S[gg[r] * 128 + col], v);
      }
    }
    qc += __shfl_xor(qc, 16); qc += __shfl_xor(qc, 32);
    sc += __shfl_xor(sc, 16); sc += __shfl_xor(sc, 32);
    if (quad == 0) {
      atomicAdd(&Qloc[col], qc);
      if (uni) atomicAdd(&Sloc[col], sc);
    }
  }
  __syncthreads();
  if (tid < 128) {
    atomicAdd(&Q[tid], Qloc[tid]);
    if (uni) atomicAdd(&S[gfirst * 128 + tid], Sloc[tid]);
  }
}

__global__ void cnt_kernel(const int* __restrict__ batch, int* __restrict__ cnt) {
  int i = blockIdx.x * 256 + threadIdx.x;
  if (i < N_NODES) atomicAdd(&cnt[batch[i]], 1);
}

// hp[g][c] = bn0_g*rsq*(S - cnt*mu) + cnt*bn0_b
__global__ void bn0hp_kernel(const float* __restrict__ S, const float* __restrict__ Q,
                             const int* __restrict__ cnt, const float* __restrict__ g0,
                             const float* __restrict__ b0, float* __restrict__ hp) {
  int c = threadIdx.x;            // 128
  float sum = 0.f;
  for (int g = 0; g < NGRAPH; ++g) sum += S[g * 128 + c];
  float mu = sum / (float)N_NODES;
  float var = Q[c] / (float)N_NODES - mu * mu;
  float gam = g0[c] * rsqrtf(var + BN_EPS);
  float bet = b0[c];
  for (int g = 0; g < NGRAPH; ++g) {
    float k = (float)cnt[g];
    hp[g * 128 + c] = gam * (S[g * 128 + c] - k * mu) + k * bet;
  }
}

// ---------------- FC head ----------------
__global__ void fc1_kernel(const float* __restrict__ hp, const float* __restrict__ w,
                           const float* __restrict__ b, const float* __restrict__ bng,
                           const float* __restrict__ bnb, float* __restrict__ z1) {
  int wv = threadIdx.x >> 6, lane = threadIdx.x & 63;
  int j = blockIdx.x * 4 + wv;    // 0..511
  float acc = b[j];
  for (int c = 0; c < 128; ++c) acc += hp[lane * 128 + c] * w[c * 512 + j];
  float s1 = acc, s2 = acc * acc;
#pragma unroll
  for (int o = 32; o; o >>= 1) { s1 += __shfl_xor(s1, o); s2 += __shfl_xor(s2, o); }
  float mu = s1 * (1.f / 64.f), var = s2 * (1.f / 64.f) - mu * mu;
  float z = bng[j] * (acc - mu) * rsqrtf(var + BN_EPS) + bnb[j];
  z1[lane * 512 + j] = fmaxf(z, 0.f);
}

__global__ void fc2_kernel(const float* __restrict__ z1, const float* __restrict__ w,
                           const float* __restrict__ b, const float* __restrict__ bng,
                           const float* __restrict__ bnb, float* __restrict__ z2) {
  int wv = threadIdx.x >> 6, lane = threadIdx.x & 63;
  int j = blockIdx.x * 4 + wv;    // 0..255
  float acc = b[j];
  for (int c = 0; c < 512; ++c) acc += z1[lane * 512 + c] * w[c * 256 + j];
  float s1 = acc, s2 = acc * acc;
#pragma unroll
  for (int o = 32; o; o >>= 1) { s1 += __shfl_xor(s1, o); s2 += __shfl_xor(s2, o); }
  float mu = s1 * (1.f / 64.f), var = s2 * (1.f / 64.f) - mu * mu;
  float z = bng[j] * (acc - mu) * rsqrtf(var + BN_EPS) + bnb[j];
  z2[lane * 256 + j] = fmaxf(z, 0.f);
}

__global__ void fc3_kernel(const float* __restrict__ z2, const float* __restrict__ w,
                           const float* __restrict__ b, const float* __restrict__ bng,
                           const float* __restrict__ bnb, float* __restrict__ out) {
  int lane = threadIdx.x;         // 64
  float acc = b[0];
  for (int c = 0; c < 256; ++c) acc += z2[lane * 256 + c] * w[c];
  float s1 = acc, s2 = acc * acc;
#pragma unroll
  for (int o = 32; o; o >>= 1) { s1 += __shfl_xor(s1, o); s2 += __shfl_xor(s2, o); }
  float mu = s1 * (1.f / 64.f), var = s2 * (1.f / 64.f) - mu * mu;
  out[lane] = bng[0] * (acc - mu) * rsqrtf(var + BN_EPS) + bnb[0];
}

extern "C" void kernel_launch(void* const* d_in, const int* in_sizes, int n_in,
                              void* d_out, int out_size, void* d_ws, size_t ws_size,
                              hipStream_t stream) {
  const float* x     = (const float*)d_in[0];
  const float* gat_w = (const float*)d_in[1];
  const float* a_src = (const float*)d_in[2];
  const float* a_dst = (const float*)d_in[3];
  const float* gbias = (const float*)d_in[4];
  const float* mlp_w = (const float*)d_in[5];
  const float* mlp_b = (const float*)d_in[6];
  const float* bn0g  = (const float*)d_in[7];
  const float* bn0b  = (const float*)d_in[8];
  const float* fc1w  = (const float*)d_in[9];
  const float* fc1b  = (const float*)d_in[10];
  const float* bn1g  = (const float*)d_in[11];
  const float* bn1b  = (const float*)d_in[12];
  const float* fc2w  = (const float*)d_in[13];
  const float* fc2b  = (const float*)d_in[14];
  const float* bn2g  = (const float*)d_in[15];
  const float* bn2b  = (const float*)d_in[16];
  const float* fc3w  = (const float*)d_in[17];
  const float* fc3b  = (const float*)d_in[18];
  const float* bn3g  = (const float*)d_in[19];
  const float* bn3b  = (const float*)d_in[20];
  const int* eidx    = (const int*)d_in[21];
  const int* batch   = (const int*)d_in[22];
  float* out = (float*)d_out;

  char* base = (char*)d_ws;
  size_t off = 0;
  auto take = [&](size_t bytes) -> char* {
    char* p = base + off;
    off += (bytes + 255) & ~(size_t)255;
    return p;
  };
  unsigned short* xp   = (unsigned short*)take((size_t)N_NODES * 256 * 2);
  unsigned short* ybf  = (unsigned short*)take((size_t)30016 * 256 * 2);   // padded for GEMM2 staging
  unsigned short* wth  = (unsigned short*)take(448 * 256 * 2);
  unsigned short* wtl  = (unsigned short*)take(448 * 256 * 2);
  unsigned short* mwth = (unsigned short*)take(128 * 256 * 2);
  unsigned short* mwtl = (unsigned short*)take(128 * 256 * 2);
  float* a_s = (float*)take((size_t)N_NODES * 2 * 4);
  float* a_d = (float*)take((size_t)N_NODES * 2 * 4);
  int* deg   = (int*)take((size_t)N_NODES * 4);
  int* offs  = (int*)take((size_t)(N_NODES + 1) * 4);
  int* cur   = (int*)take((size_t)N_NODES * 4);
  int* csr   = (int*)take((size_t)N_EDGES * 4);
  float* S   = (float*)take(NGRAPH * 128 * 4);  // 32768 B, contiguous with Q (512) and cnt (256)
  float* Q   = (float*)take(128 * 4);
  int* cnt   = (int*)take(NGRAPH * 4);
  float* hp  = (float*)take(NGRAPH * 128 * 4);
  float* z1  = (float*)take(NGRAPH * 512 * 4);
  float* z2  = (float*)take(NGRAPH * 256 * 4);

  hipMemsetAsync(deg, 0, (size_t)N_NODES * 4, stream);
  hipMemsetAsync(S, 0, (size_t)(NGRAPH * 128 * 4 + 512 + 256), stream);

  cast_w_kernel<<<576, 256, 0, stream>>>(gat_w, mlp_w, wth, wtl, mwth, mwtl);
  hist_kernel<<<3750, 256, 0, stream>>>(eidx, deg);
  scan_kernel<<<1, 1024, 0, stream>>>(deg, offs, cur, N_NODES);
  scatter_kernel<<<3750, 256, 0, stream>>>(eidx, cur, csr);
  gat_gemm_kernel<<<NB_GEMM, 256, 0, stream>>>(x, wth, wtl, a_src, a_dst, xp, a_s, a_d);
  attn_kernel<<<7500, 256, 0, stream>>>(xp, a_s, a_d, offs, csr, gbias, ybf);
  mlp_gemm_kernel<<<NB_GEMM, 256, 0, stream>>>(ybf, mwth, mwtl, mlp_b, batch, S, Q);
  cnt_kernel<<<118, 256, 0, stream>>>(batch, cnt);
  bn0hp_kernel<<<1, 128, 0, stream>>>(S, Q, cnt, bn0g, bn0b, hp);
  fc1_kernel<<<128, 256, 0, stream>>>(hp, fc1w, fc1b, bn1g, bn1b, z1);
  fc2_kernel<<<64, 256, 0, stream>>>(z1, fc2w, fc2b, bn2g, bn2b, z2);
  fc3_kernel<<<1, 64, 0, stream>>>(z2, fc3w, fc3b, bn3g, bn3b, out);

  (void)in_sizes; (void)n_in; (void)out_size; (void)ws_size;
}

// Round 3
// 498.224 us; speedup vs baseline: 1.3813x; 1.3178x over previous
//
#include <hip/hip_runtime.h>

#define N_NODES 30000
#define N_EDGES 960000
#define NGRAPH  64
#define BN_EPS  1e-5f
#define NB_GEMM 469   // ceil(30000/64)

typedef __bf16 bf16x8 __attribute__((ext_vector_type(8)));
typedef float  f32x4  __attribute__((ext_vector_type(4)));
typedef unsigned short u16x8v __attribute__((ext_vector_type(8)));

__device__ __forceinline__ unsigned short f2bf(float f) {
  union { float f; unsigned u; } v; v.f = f;
  unsigned r = (v.u + 0x7FFFu + ((v.u >> 16) & 1u)) >> 16;
  return (unsigned short)r;
}
__device__ __forceinline__ float bf2f(unsigned short u) {
  union { unsigned u; float f; } v; v.u = ((unsigned)u) << 16;
  return v.f;
}
__device__ __forceinline__ void gld_lds16(const void* g, void* l) {
  __builtin_amdgcn_global_load_lds(
      (const __attribute__((address_space(1))) unsigned int*)g,
      (__attribute__((address_space(3))) unsigned int*)l, 16, 0, 0);
}

// transpose-cast gat_w [448,256] -> wt[n][k] hi/lo, mlp_w [256,128] -> mwt[n][k] hi/lo
__global__ void cast_w_kernel(const float* __restrict__ gw, const float* __restrict__ mw,
                              unsigned short* __restrict__ wth, unsigned short* __restrict__ wtl,
                              unsigned short* __restrict__ mwth, unsigned short* __restrict__ mwtl) {
  int o = blockIdx.x * 256 + threadIdx.x;
  float v; unsigned short *ph, *pl; int oi;
  if (o < 448 * 256) {
    int n = o / 448, k = o - n * 448;
    v = gw[k * 256 + n]; ph = wth; pl = wtl; oi = o;
  } else {
    int o2 = o - 448 * 256;
    int n = o2 / 256, k = o2 - n * 256;
    v = mw[k * 128 + n]; ph = mwth; pl = mwtl; oi = o2;
  }
  unsigned short h = f2bf(v);
  ph[oi] = h; pl[oi] = f2bf(v - bf2f(h));
}

// ---------------- CSR build ----------------
__global__ void hist_kernel(const int* __restrict__ ei, int* __restrict__ deg) {
  int i = blockIdx.x * 256 + threadIdx.x;
  atomicAdd(&deg[ei[N_EDGES + i]], 1);
}

__global__ void scan_kernel(const int* __restrict__ deg, int* __restrict__ offs,
                            int* __restrict__ cur, int n) {
  __shared__ int wsum[16];
  __shared__ int wpre[16];
  __shared__ int running;
  int tid = threadIdx.x, widx = tid >> 6, lane = tid & 63;
  if (tid == 0) running = 0;
  __syncthreads();
  for (int base = 0; base < n; base += 1024) {
    int i = base + tid;
    int v = (i < n) ? deg[i] : 0;
    int s = v;
#pragma unroll
    for (int o = 1; o <= 32; o <<= 1) {
      int t = __shfl_up(s, o, 64);
      if (lane >= o) s += t;
    }
    if (lane == 63) wsum[widx] = s;
    __syncthreads();
    if (tid == 0) {
      int acc = 0;
#pragma unroll
      for (int j = 0; j < 16; ++j) { wpre[j] = acc; acc += wsum[j]; }
    }
    __syncthreads();
    int excl = running + wpre[widx] + (s - v);
    if (i < n) { offs[i] = excl; cur[i] = excl; }
    __syncthreads();
    if (tid == 0) running += wpre[15] + wsum[15];
    __syncthreads();
  }
  if (threadIdx.x == 0) offs[n] = running;
}

__global__ void scatter_kernel(const int* __restrict__ ei, int* __restrict__ cur,
                               int* __restrict__ csr) {
  int i = blockIdx.x * 256 + threadIdx.x;
  int dst = ei[N_EDGES + i], src = ei[i];
  int pos = atomicAdd(&cur[dst], 1);
  csr[pos] = src;
}

// cnt[g] via binary search on sorted batch — zero atomics (old version: 141us of
// atomic serialization, 30000 atomics onto 2 cachelines)
__global__ void cnt_kernel(const int* __restrict__ batch, int* __restrict__ cnt) {
  int g = threadIdx.x;          // 64 threads
  int lo = 0, hi = N_NODES;
  while (lo < hi) { int mid = (lo + hi) >> 1; if (batch[mid] < g) lo = mid + 1; else hi = mid; }
  int start = lo;
  lo = 0; hi = N_NODES;
  while (lo < hi) { int mid = (lo + hi) >> 1; if (batch[mid] < g + 1) lo = mid + 1; else hi = mid; }
  cnt[g] = lo - start;
}

// ---------------- GEMM1 fused: cast(x) -> xp = x@gat_w (split bf16) -> xp bf16 + a_s/a_d ----------------
__global__ void __launch_bounds__(256) gat_gemm_kernel(
    const float* __restrict__ x,
    const unsigned short* __restrict__ wth, const unsigned short* __restrict__ wtl,
    const float* __restrict__ asrc, const float* __restrict__ adst,
    unsigned short* __restrict__ xp, float* __restrict__ a_s, float* __restrict__ a_d) {
  __shared__ unsigned short Ah[4 * 64 * 8], Al[4 * 64 * 8];      // 4KB + 4KB
  __shared__ unsigned short Bh[4 * 256 * 8], Bl[4 * 256 * 8];    // 16KB + 16KB
  int tid = threadIdx.x;
  int w = tid >> 6, lane = tid & 63;
  int m = lane & 15, quad = lane >> 4;
  int r0 = blockIdx.x * 64;
  int arow_g = r0 + lane;
  bool avalid = arow_g < N_NODES;
  const float* axp = x + (size_t)(avalid ? arow_g : 0) * 448 + w * 8;

  f32x4 acc[16];
#pragma unroll
  for (int c = 0; c < 16; ++c) acc[c] = (f32x4){0.f, 0.f, 0.f, 0.f};

  for (int kc = 0; kc < 14; ++kc) {
    int k0 = kc * 32;
    float4 v0 = {0.f, 0.f, 0.f, 0.f}, v1 = {0.f, 0.f, 0.f, 0.f};
    if (avalid) {
      v0 = *(const float4*)(axp + k0);
      v1 = *(const float4*)(axp + k0 + 4);
    }
    float vv[8] = {v0.x, v0.y, v0.z, v0.w, v1.x, v1.y, v1.z, v1.w};
    u16x8v hv, lv;
#pragma unroll
    for (int j = 0; j < 8; ++j) {
      unsigned short h = f2bf(vv[j]);
      hv[j] = h;
      lv[j] = f2bf(vv[j] - bf2f(h));
    }
    *(u16x8v*)(Ah + w * 512 + lane * 8) = hv;
    *(u16x8v*)(Al + w * 512 + lane * 8) = lv;
#pragma unroll
    for (int i = 0; i < 4; ++i) {
      int n = i * 64 + lane;
      gld_lds16(wth + (size_t)n * 448 + k0 + w * 8, Bh + w * 2048 + i * 512);
      gld_lds16(wtl + (size_t)n * 448 + k0 + w * 8, Bl + w * 2048 + i * 512);
    }
    __syncthreads();
    bf16x8 ah = *(const bf16x8*)(Ah + quad * 512 + (w * 16 + m) * 8);
    bf16x8 al = *(const bf16x8*)(Al + quad * 512 + (w * 16 + m) * 8);
#pragma unroll
    for (int c = 0; c < 16; ++c) {
      bf16x8 bh = *(const bf16x8*)(Bh + quad * 2048 + (c * 16 + m) * 8);
      bf16x8 bl = *(const bf16x8*)(Bl + quad * 2048 + (c * 16 + m) * 8);
      acc[c] = __builtin_amdgcn_mfma_f32_16x16x32_bf16(ah, bh, acc[c], 0, 0, 0);
      acc[c] = __builtin_amdgcn_mfma_f32_16x16x32_bf16(ah, bl, acc[c], 0, 0, 0);
      acc[c] = __builtin_amdgcn_mfma_f32_16x16x32_bf16(al, bh, acc[c], 0, 0, 0);
    }
    __syncthreads();
  }
  float ps0[4] = {0, 0, 0, 0}, ps1[4] = {0, 0, 0, 0};
  float pd0[4] = {0, 0, 0, 0}, pd1[4] = {0, 0, 0, 0};
#pragma unroll
  for (int c = 0; c < 16; ++c) {
    int col = c * 16 + m;
    float sa = asrc[col], da = adst[col];
#pragma unroll
    for (int r = 0; r < 4; ++r) {
      float v = acc[c][r];
      if (c < 8) { ps0[r] += v * sa; pd0[r] += v * da; }
      else       { ps1[r] += v * sa; pd1[r] += v * da; }
    }
  }
#pragma unroll
  for (int o = 1; o <= 8; o <<= 1) {
#pragma unroll
    for (int r = 0; r < 4; ++r) {
      ps0[r] += __shfl_xor(ps0[r], o);
      ps1[r] += __shfl_xor(ps1[r], o);
      pd0[r] += __shfl_xor(pd0[r], o);
      pd1[r] += __shfl_xor(pd1[r], o);
    }
  }
  int rowb = r0 + w * 16 + quad * 4;
  if (m == 0) {
#pragma unroll
    for (int r = 0; r < 4; ++r) {
      int row = rowb + r;
      if (row < N_NODES) {
        a_s[2 * row] = ps0[r]; a_s[2 * row + 1] = ps1[r];
        a_d[2 * row] = pd0[r]; a_d[2 * row + 1] = pd1[r];
      }
    }
  }
#pragma unroll
  for (int r = 0; r < 4; ++r) {
    int row = rowb + r;
    if (row < N_NODES) {
#pragma unroll
      for (int c = 0; c < 16; ++c)
        xp[(size_t)row * 256 + c * 16 + m] = f2bf(acc[c][r]);
    }
  }
}

// ---------------- attention: one wave per dst node ----------------
__global__ void attn_kernel(const unsigned short* __restrict__ xp,
                            const float* __restrict__ a_s, const float* __restrict__ a_d,
                            const int* __restrict__ offs, const int* __restrict__ csr,
                            const float* __restrict__ bias, unsigned short* __restrict__ y) {
  int nid = (blockIdx.x * 256 + (int)threadIdx.x) >> 6;
  int lane = threadIdx.x & 63;
  int head = lane >> 5;
  float d0 = a_d[2 * nid], d1 = a_d[2 * nid + 1];
  float s0 = a_s[2 * nid], s1 = a_s[2 * nid + 1];
  int beg = offs[nid], end = offs[nid + 1];
  int deg = end - beg;
  float e0s = s0 + d0; e0s = e0s > 0.f ? e0s : 0.2f * e0s;
  float e1s = s1 + d1; e1s = e1s > 0.f ? e1s : 0.2f * e1s;
  float ax = 0.f, ay = 0.f, az = 0.f, aw = 0.f, wsum = 0.f;

  if (deg <= 64) {
    // ---- fast path: cache edges in registers, exp once/edge, shfl broadcast ----
    int sreg = 0;
    float e0 = -1e30f, e1 = -1e30f;
    if (lane < deg) {
      sreg = csr[beg + lane];
      float as0 = a_s[2 * sreg], as1 = a_s[2 * sreg + 1];
      e0 = as0 + d0; e0 = e0 > 0.f ? e0 : 0.2f * e0;
      e1 = as1 + d1; e1 = e1 > 0.f ? e1 : 0.2f * e1;
    }
    float m0 = fmaxf(e0, e0s), m1 = fmaxf(e1, e1s);
#pragma unroll
    for (int o = 32; o; o >>= 1) {
      m0 = fmaxf(m0, __shfl_xor(m0, o));
      m1 = fmaxf(m1, __shfl_xor(m1, o));
    }
    float p0 = 0.f, p1 = 0.f;
    if (lane < deg) { p0 = __expf(e0 - m0); p1 = __expf(e1 - m1); }
    float ws0 = p0, ws1 = p1;
#pragma unroll
    for (int o = 32; o; o >>= 1) { ws0 += __shfl_xor(ws0, o); ws1 += __shfl_xor(ws1, o); }
    float wself = __expf((head ? e1s : e0s) - (head ? m1 : m0));
    wsum = (head ? ws1 : ws0) + wself;
    {
      ushort4 u = *(const ushort4*)(xp + (size_t)nid * 256 + lane * 4);
      ax = wself * bf2f(u.x); ay = wself * bf2f(u.y);
      az = wself * bf2f(u.z); aw = wself * bf2f(u.w);
    }
    for (int j = 0; j < deg; ++j) {
      int s = __shfl(sreg, j);
      float w0 = __shfl(p0, j), w1 = __shfl(p1, j);
      float wgt = head ? w1 : w0;
      ushort4 u = *(const ushort4*)(xp + (size_t)s * 256 + lane * 4);
      ax += wgt * bf2f(u.x); ay += wgt * bf2f(u.y);
      az += wgt * bf2f(u.z); aw += wgt * bf2f(u.w);
    }
  } else {
    // ---- slow path (deg > 64, vanishingly rare) ----
    float m0 = e0s, m1 = e1s;
    for (int j = beg + lane; j < end; j += 64) {
      int s = csr[j];
      float as0 = a_s[2 * s], as1 = a_s[2 * s + 1];
      float e0 = as0 + d0; e0 = e0 > 0.f ? e0 : 0.2f * e0;
      float e1 = as1 + d1; e1 = e1 > 0.f ? e1 : 0.2f * e1;
      m0 = fmaxf(m0, e0); m1 = fmaxf(m1, e1);
    }
#pragma unroll
    for (int o = 32; o; o >>= 1) {
      m0 = fmaxf(m0, __shfl_xor(m0, o));
      m1 = fmaxf(m1, __shfl_xor(m1, o));
    }
    float dh = head ? d1 : d0;
    float mh = head ? m1 : m0;
    {
      float e = head ? e1s : e0s;
      float wgt = __expf(e - mh);
      ushort4 u = *(const ushort4*)(xp + (size_t)nid * 256 + lane * 4);
      ax = wgt * bf2f(u.x); ay = wgt * bf2f(u.y); az = wgt * bf2f(u.z); aw = wgt * bf2f(u.w);
      wsum = wgt;
    }
    for (int j = beg; j < end; ++j) {
      int s = csr[j];
      float as = a_s[2 * s + head];
      float e = as + dh; e = e > 0.f ? e : 0.2f * e;
      float wgt = __expf(e - mh);
      ushort4 u = *(const ushort4*)(xp + (size_t)s * 256 + lane * 4);
      ax += wgt * bf2f(u.x); ay += wgt * bf2f(u.y); az += wgt * bf2f(u.z); aw += wgt * bf2f(u.w);
      wsum += wgt;
    }
  }

  float inv = 1.f / wsum;
  float4 b4 = *(const float4*)(bias + lane * 4);
  float o0 = ax * inv + b4.x, o1 = ay * inv + b4.y;
  float o2 = az * inv + b4.z, o3 = aw * inv + b4.w;
  o0 = o0 > 0.f ? o0 : __expf(o0) - 1.f;
  o1 = o1 > 0.f ? o1 : __expf(o1) - 1.f;
  o2 = o2 > 0.f ? o2 : __expf(o2) - 1.f;
  o3 = o3 > 0.f ? o3 : __expf(o3) - 1.f;
  ushort4 yo; yo.x = f2bf(o0); yo.y = f2bf(o1); yo.z = f2bf(o2); yo.w = f2bf(o3);
  *(ushort4*)(y + (size_t)nid * 256 + lane * 4) = yo;
}

// ---------------- GEMM2 fused: t = y@mlp_w + b, pooled into S[g][c], Q[c] ----------------
__global__ void __launch_bounds__(256) mlp_gemm_kernel(
    const unsigned short* __restrict__ y,
    const unsigned short* __restrict__ mwth, const unsigned short* __restrict__ mwtl,
    const float* __restrict__ mlp_b, const int* __restrict__ batch,
    float* __restrict__ S, float* __restrict__ Q) {
  __shared__ unsigned short Ahs[4 * 64 * 8];
  __shared__ unsigned short Bh[4 * 128 * 8], Bl[4 * 128 * 8];
  __shared__ float Sloc[128], Qloc[128];
  int tid = threadIdx.x;
  int w = tid >> 6, lane = tid & 63;
  int m = lane & 15, quad = lane >> 4;
  int r0 = blockIdx.x * 64;
  if (tid < 128) { Sloc[tid] = 0.f; Qloc[tid] = 0.f; }

  f32x4 acc[8];
#pragma unroll
  for (int c = 0; c < 8; ++c) acc[c] = (f32x4){0.f, 0.f, 0.f, 0.f};

  for (int kc = 0; kc < 8; ++kc) {
    int k0 = kc * 32;
    gld_lds16(y + (size_t)(r0 + lane) * 256 + k0 + w * 8, Ahs + w * 512);
#pragma unroll
    for (int i = 0; i < 2; ++i) {
      int n = i * 64 + lane;
      gld_lds16(mwth + (size_t)n * 256 + k0 + w * 8, Bh + w * 1024 + i * 512);
      gld_lds16(mwtl + (size_t)n * 256 + k0 + w * 8, Bl + w * 1024 + i * 512);
    }
    __syncthreads();
    bf16x8 ah = *(const bf16x8*)(Ahs + quad * 512 + (w * 16 + m) * 8);
#pragma unroll
    for (int c = 0; c < 8; ++c) {
      bf16x8 bh = *(const bf16x8*)(Bh + quad * 1024 + (c * 16 + m) * 8);
      bf16x8 bl = *(const bf16x8*)(Bl + quad * 1024 + (c * 16 + m) * 8);
      acc[c] = __builtin_amdgcn_mfma_f32_16x16x32_bf16(ah, bh, acc[c], 0, 0, 0);
      acc[c] = __builtin_amdgcn_mfma_f32_16x16x32_bf16(ah, bl, acc[c], 0, 0, 0);
    }
    __syncthreads();
  }
  int rowb = r0 + w * 16 + quad * 4;
  int gfirst = batch[r0];
  int glast = batch[min(r0 + 63, N_NODES - 1)];
  bool uni = (gfirst == glast);
  bool valid[4]; int gg[4];
#pragma unroll
  for (int r = 0; r < 4; ++r) {
    int row = rowb + r;
    valid[r] = row < N_NODES;
    gg[r] = (!uni && valid[r]) ? batch[row] : gfirst;
  }
#pragma unroll
  for (int c = 0; c < 8; ++c) {
    int col = c * 16 + m;
    float bv = mlp_b[col];
    float sc = 0.f, qc = 0.f;
#pragma unroll
    for (int r = 0; r < 4; ++r) {
      if (valid[r]) {
        float v = acc[c][r] + bv;
        qc += v * v;
        if (uni) sc += v;
        else atomicAdd(&S[gg[r] * 128 + col], v);
      }
    }
    qc += __shfl_xor(qc, 16); qc += __shfl_xor(qc, 32);
    sc += __shfl_xor(sc, 16); sc += __shfl_xor(sc, 32);
    if (quad == 0) {
      atomicAdd(&Qloc[col], qc);
      if (uni) atomicAdd(&Sloc[col], sc);
    }
  }
  __syncthreads();
  if (tid < 128) {
    atomicAdd(&Q[tid], Qloc[tid]);
    if (uni) atomicAdd(&S[gfirst * 128 + tid], Sloc[tid]);
  }
}

// hp[g][c] = bn0_g*rsq*(S - cnt*mu) + cnt*bn0_b
__global__ void bn0hp_kernel(const float* __restrict__ S, const float* __restrict__ Q,
                             const int* __restrict__ cnt, const float* __restrict__ g0,
                             const float* __restrict__ b0, float* __restrict__ hp) {
  int c = threadIdx.x;            // 128
  float sum = 0.f;
  for (int g = 0; g < NGRAPH; ++g) sum += S[g * 128 + c];
  float mu = sum / (float)N_NODES;
  float var = Q[c] / (float)N_NODES - mu * mu;
  float gam = g0[c] * rsqrtf(var + BN_EPS);
  float bet = b0[c];
  for (int g = 0; g < NGRAPH; ++g) {
    float k = (float)cnt[g];
    hp[g * 128 + c] = gam * (S[g * 128 + c] - k * mu) + k * bet;
  }
}

// ---------------- FC head ----------------
__global__ void fc1_kernel(const float* __restrict__ hp, const float* __restrict__ w,
                           const float* __restrict__ b, const float* __restrict__ bng,
                           const float* __restrict__ bnb, float* __restrict__ z1) {
  int wv = threadIdx.x >> 6, lane = threadIdx.x & 63;
  int j = blockIdx.x * 4 + wv;    // 0..511
  float acc = b[j];
  for (int c = 0; c < 128; ++c) acc += hp[lane * 128 + c] * w[c * 512 + j];
  float s1 = acc, s2 = acc * acc;
#pragma unroll
  for (int o = 32; o; o >>= 1) { s1 += __shfl_xor(s1, o); s2 += __shfl_xor(s2, o); }
  float mu = s1 * (1.f / 64.f), var = s2 * (1.f / 64.f) - mu * mu;
  float z = bng[j] * (acc - mu) * rsqrtf(var + BN_EPS) + bnb[j];
  z1[lane * 512 + j] = fmaxf(z, 0.f);
}

__global__ void fc2_kernel(const float* __restrict__ z1, const float* __restrict__ w,
                           const float* __restrict__ b, const float* __restrict__ bng,
                           const float* __restrict__ bnb, float* __restrict__ z2) {
  int wv = threadIdx.x >> 6, lane = threadIdx.x & 63;
  int j = blockIdx.x * 4 + wv;    // 0..255
  float acc = b[j];
  for (int c = 0; c < 512; ++c) acc += z1[lane * 512 + c] * w[c * 256 + j];
  float s1 = acc, s2 = acc * acc;
#pragma unroll
  for (int o = 32; o; o >>= 1) { s1 += __shfl_xor(s1, o); s2 += __shfl_xor(s2, o); }
  float mu = s1 * (1.f / 64.f), var = s2 * (1.f / 64.f) - mu * mu;
  float z = bng[j] * (acc - mu) * rsqrtf(var + BN_EPS) + bnb[j];
  z2[lane * 256 + j] = fmaxf(z, 0.f);
}

__global__ void fc3_kernel(const float* __restrict__ z2, const float* __restrict__ w,
                           const float* __restrict__ b, const float* __restrict__ bng,
                           const float* __restrict__ bnb, float* __restrict__ out) {
  int lane = threadIdx.x;         // 64
  float acc = b[0];
  for (int c = 0; c < 256; ++c) acc += z2[lane * 256 + c] * w[c];
  float s1 = acc, s2 = acc * acc;
#pragma unroll
  for (int o = 32; o; o >>= 1) { s1 += __shfl_xor(s1, o); s2 += __shfl_xor(s2, o); }
  float mu = s1 * (1.f / 64.f), var = s2 * (1.f / 64.f) - mu * mu;
  out[lane] = bng[0] * (acc - mu) * rsqrtf(var + BN_EPS) + bnb[0];
}

extern "C" void kernel_launch(void* const* d_in, const int* in_sizes, int n_in,
                              void* d_out, int out_size, void* d_ws, size_t ws_size,
                              hipStream_t stream) {
  const float* x     = (const float*)d_in[0];
  const float* gat_w = (const float*)d_in[1];
  const float* a_src = (const float*)d_in[2];
  const float* a_dst = (const float*)d_in[3];
  const float* gbias = (const float*)d_in[4];
  const float* mlp_w = (const float*)d_in[5];
  const float* mlp_b = (const float*)d_in[6];
  const float* bn0g  = (const float*)d_in[7];
  const float* bn0b  = (const float*)d_in[8];
  const float* fc1w  = (const float*)d_in[9];
  const float* fc1b  = (const float*)d_in[10];
  const float* bn1g  = (const float*)d_in[11];
  const float* bn1b  = (const float*)d_in[12];
  const float* fc2w  = (const float*)d_in[13];
  const float* fc2b  = (const float*)d_in[14];
  const float* bn2g  = (const float*)d_in[15];
  const float* bn2b  = (const float*)d_in[16];
  const float* fc3w  = (const float*)d_in[17];
  const float* fc3b  = (const float*)d_in[18];
  const float* bn3g  = (const float*)d_in[19];
  const float* bn3b  = (const float*)d_in[20];
  const int* eidx    = (const int*)d_in[21];
  const int* batch   = (const int*)d_in[22];
  float* out = (float*)d_out;

  char* base = (char*)d_ws;
  size_t off = 0;
  auto take = [&](size_t bytes) -> char* {
    char* p = base + off;
    off += (bytes + 255) & ~(size_t)255;
    return p;
  };
  unsigned short* xp   = (unsigned short*)take((size_t)N_NODES * 256 * 2);
  unsigned short* ybf  = (unsigned short*)take((size_t)30016 * 256 * 2);
  unsigned short* wth  = (unsigned short*)take(448 * 256 * 2);
  unsigned short* wtl  = (unsigned short*)take(448 * 256 * 2);
  unsigned short* mwth = (unsigned short*)take(128 * 256 * 2);
  unsigned short* mwtl = (unsigned short*)take(128 * 256 * 2);
  float* a_s = (float*)take((size_t)N_NODES * 2 * 4);
  float* a_d = (float*)take((size_t)N_NODES * 2 * 4);
  int* deg   = (int*)take((size_t)N_NODES * 4);
  int* offs  = (int*)take((size_t)(N_NODES + 1) * 4);
  int* cur   = (int*)take((size_t)N_NODES * 4);
  int* csr   = (int*)take((size_t)N_EDGES * 4);
  float* S   = (float*)take(NGRAPH * 128 * 4);
  float* Q   = (float*)take(128 * 4);
  int* cnt   = (int*)take(NGRAPH * 4);
  float* hp  = (float*)take(NGRAPH * 128 * 4);
  float* z1  = (float*)take(NGRAPH * 512 * 4);
  float* z2  = (float*)take(NGRAPH * 256 * 4);

  hipMemsetAsync(deg, 0, (size_t)N_NODES * 4, stream);
  hipMemsetAsync(S, 0, (size_t)(NGRAPH * 128 * 4 + 512), stream);

  cast_w_kernel<<<576, 256, 0, stream>>>(gat_w, mlp_w, wth, wtl, mwth, mwtl);
  hist_kernel<<<3750, 256, 0, stream>>>(eidx, deg);
  scan_kernel<<<1, 1024, 0, stream>>>(deg, offs, cur, N_NODES);
  scatter_kernel<<<3750, 256, 0, stream>>>(eidx, cur, csr);
  cnt_kernel<<<1, 64, 0, stream>>>(batch, cnt);
  gat_gemm_kernel<<<NB_GEMM, 256, 0, stream>>>(x, wth, wtl, a_src, a_dst, xp, a_s, a_d);
  attn_kernel<<<7500, 256, 0, stream>>>(xp, a_s, a_d, offs, csr, gbias, ybf);
  mlp_gemm_kernel<<<NB_GEMM, 256, 0, stream>>>(ybf, mwth, mwtl, mlp_b, batch, S, Q);
  bn0hp_kernel<<<1, 128, 0, stream>>>(S, Q, cnt, bn0g, bn0b, hp);
  fc1_kernel<<<128, 256, 0, stream>>>(hp, fc1w, fc1b, bn1g, bn1b, z1);
  fc2_kernel<<<64, 256, 0, stream>>>(z1, fc2w, fc2b, bn2g, bn2b, z2);
  fc3_kernel<<<1, 64, 0, stream>>>(z2, fc3w, fc3b, bn3g, bn3b, out);

  (void)in_sizes; (void)n_in; (void)out_size; (void)ws_size;
}

// Round 5
// 473.828 us; speedup vs baseline: 1.4524x; 1.0515x over previous
//
#include <hip/hip_runtime.h>

#define N_NODES 30000
#define N_EDGES 960000
#define NGRAPH  64
#define BN_EPS  1e-5f
#define NB_GEMM 469   // ceil(30000/64)

typedef __bf16 bf16x8 __attribute__((ext_vector_type(8)));
typedef float  f32x4  __attribute__((ext_vector_type(4)));
typedef unsigned short u16x8v __attribute__((ext_vector_type(8)));

__device__ __forceinline__ unsigned short f2bf(float f) {
  union { float f; unsigned u; } v; v.f = f;
  unsigned r = (v.u + 0x7FFFu + ((v.u >> 16) & 1u)) >> 16;
  return (unsigned short)r;
}
__device__ __forceinline__ float bf2f(unsigned short u) {
  union { unsigned u; float f; } v; v.u = ((unsigned)u) << 16;
  return v.f;
}
// unpack low/high bf16 of a 32-bit word (hi needs only an AND)
__device__ __forceinline__ float bflo(unsigned w) {
  union { unsigned u; float f; } v; v.u = w << 16; return v.f;
}
__device__ __forceinline__ float bfhi(unsigned w) {
  union { unsigned u; float f; } v; v.u = w & 0xFFFF0000u; return v.f;
}
__device__ __forceinline__ void gld_lds16(const void* g, void* l) {
  __builtin_amdgcn_global_load_lds(
      (const __attribute__((address_space(1))) unsigned int*)g,
      (__attribute__((address_space(3))) unsigned int*)l, 16, 0, 0);
}

// merged: blocks 0..575 transpose-cast weights; block 576 computes cnt[] by binary search
__global__ void castw_cnt_kernel(const float* __restrict__ gw, const float* __restrict__ mw,
                                 unsigned short* __restrict__ wth, unsigned short* __restrict__ wtl,
                                 unsigned short* __restrict__ mwth, unsigned short* __restrict__ mwtl,
                                 const int* __restrict__ batch, int* __restrict__ cnt) {
  if (blockIdx.x == 576) {
    if (threadIdx.x < 64) {
      int g = threadIdx.x;
      int lo = 0, hi = N_NODES;
      while (lo < hi) { int mid = (lo + hi) >> 1; if (batch[mid] < g) lo = mid + 1; else hi = mid; }
      int start = lo;
      lo = 0; hi = N_NODES;
      while (lo < hi) { int mid = (lo + hi) >> 1; if (batch[mid] < g + 1) lo = mid + 1; else hi = mid; }
      cnt[g] = lo - start;
    }
    return;
  }
  int o = blockIdx.x * 256 + threadIdx.x;
  float v; unsigned short *ph, *pl; int oi;
  if (o < 448 * 256) {
    int n = o / 448, k = o - n * 448;
    v = gw[k * 256 + n]; ph = wth; pl = wtl; oi = o;
  } else {
    int o2 = o - 448 * 256;
    int n = o2 / 256, k = o2 - n * 256;
    v = mw[k * 128 + n]; ph = mwth; pl = mwtl; oi = o2;
  }
  unsigned short h = f2bf(v);
  ph[oi] = h; pl[oi] = f2bf(v - bf2f(h));
}

// ---------------- CSR build ----------------
__global__ void hist_kernel(const int* __restrict__ ei, int* __restrict__ deg) {
  int i = (blockIdx.x * 256 + threadIdx.x) * 4;
  if (i < N_EDGES) {
    int4 d = *(const int4*)(ei + N_EDGES + i);
    atomicAdd(&deg[d.x], 1); atomicAdd(&deg[d.y], 1);
    atomicAdd(&deg[d.z], 1); atomicAdd(&deg[d.w], 1);
  }
}

// 8 elements/thread, 4 chunks of 8192
__global__ void scan_kernel(const int* __restrict__ deg, int* __restrict__ offs,
                            int* __restrict__ cur, int n) {
  __shared__ int wsum[16], wpre[16];
  __shared__ int running;
  int tid = threadIdx.x, widx = tid >> 6, lane = tid & 63;
  if (tid == 0) running = 0;
  __syncthreads();
  for (int base = 0; base < n; base += 8192) {
    int i0 = base + tid * 8;
    int v[8];
#pragma unroll
    for (int j = 0; j < 8; ++j) { int i = i0 + j; v[j] = (i < n) ? deg[i] : 0; }
    int pre[8]; int t = 0;
#pragma unroll
    for (int j = 0; j < 8; ++j) { pre[j] = t; t += v[j]; }
    int s = t;
#pragma unroll
    for (int o = 1; o <= 32; o <<= 1) {
      int tt = __shfl_up(s, o, 64);
      if (lane >= o) s += tt;
    }
    if (lane == 63) wsum[widx] = s;
    __syncthreads();
    if (tid == 0) {
      int a = 0;
#pragma unroll
      for (int j = 0; j < 16; ++j) { wpre[j] = a; a += wsum[j]; }
    }
    __syncthreads();
    int boff = running + wpre[widx] + (s - t);
#pragma unroll
    for (int j = 0; j < 8; ++j) {
      int i = i0 + j;
      if (i < n) { int p = boff + pre[j]; offs[i] = p; cur[i] = p; }
    }
    __syncthreads();
    if (tid == 0) running += wpre[15] + wsum[15];
    __syncthreads();
  }
  if (tid == 0) offs[n] = running;
}

__global__ void scatter_kernel(const int* __restrict__ ei, int* __restrict__ cur,
                               int* __restrict__ csr) {
  int i = (blockIdx.x * 256 + threadIdx.x) * 4;
  if (i < N_EDGES) {
    int4 d = *(const int4*)(ei + N_EDGES + i);
    int4 sv = *(const int4*)(ei + i);
    int p0 = atomicAdd(&cur[d.x], 1); csr[p0] = sv.x;
    int p1 = atomicAdd(&cur[d.y], 1); csr[p1] = sv.y;
    int p2 = atomicAdd(&cur[d.z], 1); csr[p2] = sv.z;
    int p3 = atomicAdd(&cur[d.w], 1); csr[p3] = sv.w;
  }
}

// ---------------- GEMM1 fused: cast(x) -> xp = x@gat_w (split bf16) -> xp bf16 + a_s/a_d ----------------
__global__ void __launch_bounds__(256) gat_gemm_kernel(
    const float* __restrict__ x,
    const unsigned short* __restrict__ wth, const unsigned short* __restrict__ wtl,
    const float* __restrict__ asrc, const float* __restrict__ adst,
    unsigned short* __restrict__ xp, float* __restrict__ a_s, float* __restrict__ a_d) {
  __shared__ unsigned short Ah[4 * 64 * 8], Al[4 * 64 * 8];
  __shared__ unsigned short Bh[4 * 256 * 8], Bl[4 * 256 * 8];
  int tid = threadIdx.x;
  int w = tid >> 6, lane = tid & 63;
  int m = lane & 15, quad = lane >> 4;
  int r0 = blockIdx.x * 64;
  int arow_g = r0 + lane;
  bool avalid = arow_g < N_NODES;
  const float* axp = x + (size_t)(avalid ? arow_g : 0) * 448 + w * 8;

  f32x4 acc[16];
#pragma unroll
  for (int c = 0; c < 16; ++c) acc[c] = (f32x4){0.f, 0.f, 0.f, 0.f};

  for (int kc = 0; kc < 14; ++kc) {
    int k0 = kc * 32;
    float4 v0 = {0.f, 0.f, 0.f, 0.f}, v1 = {0.f, 0.f, 0.f, 0.f};
    if (avalid) {
      v0 = *(const float4*)(axp + k0);
      v1 = *(const float4*)(axp + k0 + 4);
    }
    float vv[8] = {v0.x, v0.y, v0.z, v0.w, v1.x, v1.y, v1.z, v1.w};
    u16x8v hv, lv;
#pragma unroll
    for (int j = 0; j < 8; ++j) {
      unsigned short h = f2bf(vv[j]);
      hv[j] = h;
      lv[j] = f2bf(vv[j] - bf2f(h));
    }
    *(u16x8v*)(Ah + w * 512 + lane * 8) = hv;
    *(u16x8v*)(Al + w * 512 + lane * 8) = lv;
#pragma unroll
    for (int i = 0; i < 4; ++i) {
      int n = i * 64 + lane;
      gld_lds16(wth + (size_t)n * 448 + k0 + w * 8, Bh + w * 2048 + i * 512);
      gld_lds16(wtl + (size_t)n * 448 + k0 + w * 8, Bl + w * 2048 + i * 512);
    }
    __syncthreads();
    bf16x8 ah = *(const bf16x8*)(Ah + quad * 512 + (w * 16 + m) * 8);
    bf16x8 al = *(const bf16x8*)(Al + quad * 512 + (w * 16 + m) * 8);
#pragma unroll
    for (int c = 0; c < 16; ++c) {
      bf16x8 bh = *(const bf16x8*)(Bh + quad * 2048 + (c * 16 + m) * 8);
      bf16x8 bl = *(const bf16x8*)(Bl + quad * 2048 + (c * 16 + m) * 8);
      acc[c] = __builtin_amdgcn_mfma_f32_16x16x32_bf16(ah, bh, acc[c], 0, 0, 0);
      acc[c] = __builtin_amdgcn_mfma_f32_16x16x32_bf16(ah, bl, acc[c], 0, 0, 0);
      acc[c] = __builtin_amdgcn_mfma_f32_16x16x32_bf16(al, bh, acc[c], 0, 0, 0);
    }
    __syncthreads();
  }
  float ps0[4] = {0, 0, 0, 0}, ps1[4] = {0, 0, 0, 0};
  float pd0[4] = {0, 0, 0, 0}, pd1[4] = {0, 0, 0, 0};
#pragma unroll
  for (int c = 0; c < 16; ++c) {
    int col = c * 16 + m;
    float sa = asrc[col], da = adst[col];
#pragma unroll
    for (int r = 0; r < 4; ++r) {
      float v = acc[c][r];
      if (c < 8) { ps0[r] += v * sa; pd0[r] += v * da; }
      else       { ps1[r] += v * sa; pd1[r] += v * da; }
    }
  }
#pragma unroll
  for (int o = 1; o <= 8; o <<= 1) {
#pragma unroll
    for (int r = 0; r < 4; ++r) {
      ps0[r] += __shfl_xor(ps0[r], o);
      ps1[r] += __shfl_xor(ps1[r], o);
      pd0[r] += __shfl_xor(pd0[r], o);
      pd1[r] += __shfl_xor(pd1[r], o);
    }
  }
  int rowb = r0 + w * 16 + quad * 4;
  if (m == 0) {
#pragma unroll
    for (int r = 0; r < 4; ++r) {
      int row = rowb + r;
      if (row < N_NODES) {
        a_s[2 * row] = ps0[r]; a_s[2 * row + 1] = ps1[r];
        a_d[2 * row] = pd0[r]; a_d[2 * row + 1] = pd1[r];
      }
    }
  }
#pragma unroll
  for (int r = 0; r < 4; ++r) {
    int row = rowb + r;
    if (row < N_NODES) {
#pragma unroll
      for (int c = 0; c < 16; ++c)
        xp[(size_t)row * 256 + c * 16 + m] = f2bf(acc[c][r]);
    }
  }
}

// ---------------- attention: one wave per dst node; 2 edges/iter (32 lanes x 16B per row) ----------------
// NOTE: every __shfl is UNCONDITIONAL (never inside a divergent ternary) —
// ds_bpermute from an inactive lane is undefined; that was the R4 bug.
__global__ void attn_kernel(const unsigned short* __restrict__ xp,
                            const float* __restrict__ a_s, const float* __restrict__ a_d,
                            const int* __restrict__ offs, const int* __restrict__ csr,
                            const float* __restrict__ bias, unsigned short* __restrict__ y) {
  int nid = (blockIdx.x * 256 + (int)threadIdx.x) >> 6;
  int lane = threadIdx.x & 63;
  int l32 = lane & 31;
  int grp = lane >> 5;        // which edge of the pair this lane handles
  int h2 = l32 >> 4;          // head of this lane's 8-channel block
  float d0 = a_d[2 * nid], d1 = a_d[2 * nid + 1];
  float s0 = a_s[2 * nid], s1 = a_s[2 * nid + 1];
  int beg = offs[nid], end = offs[nid + 1];
  int deg = end - beg;
  float e0s = s0 + d0; e0s = e0s > 0.f ? e0s : 0.2f * e0s;
  float e1s = s1 + d1; e1s = e1s > 0.f ? e1s : 0.2f * e1s;

  if (deg <= 64) {
    // per-lane edge cache (lane L holds edge L)
    int sreg = nid;
    float p0 = 0.f, p1 = 0.f;
    float e0 = -1e30f, e1 = -1e30f;
    if (lane < deg) {
      sreg = csr[beg + lane];
      float as0 = a_s[2 * sreg], as1 = a_s[2 * sreg + 1];
      e0 = as0 + d0; e0 = e0 > 0.f ? e0 : 0.2f * e0;
      e1 = as1 + d1; e1 = e1 > 0.f ? e1 : 0.2f * e1;
    }
    float m0 = fmaxf(e0, e0s), m1 = fmaxf(e1, e1s);
#pragma unroll
    for (int o = 32; o; o >>= 1) {
      m0 = fmaxf(m0, __shfl_xor(m0, o));
      m1 = fmaxf(m1, __shfl_xor(m1, o));
    }
    if (lane < deg) { p0 = __expf(e0 - m0); p1 = __expf(e1 - m1); }
    float ws0 = p0, ws1 = p1;
#pragma unroll
    for (int o = 32; o; o >>= 1) { ws0 += __shfl_xor(ws0, o); ws1 += __shfl_xor(ws1, o); }
    float wself0 = __expf(e0s - m0), wself1 = __expf(e1s - m1);
    float inv = 1.f / (h2 ? (ws1 + wself1) : (ws0 + wself0));

    float acc[8] = {0.f, 0.f, 0.f, 0.f, 0.f, 0.f, 0.f, 0.f};
    const unsigned* xpw = (const unsigned*)xp;  // 32-bit view (2 bf16/word)
    // self row: only group 0 contributes (avoid double count after merge)
    {
      float wgt = grp ? 0.f : (h2 ? wself1 : wself0);
      uint4 u = *(const uint4*)(xpw + (size_t)nid * 128 + l32 * 4);
      acc[0] += wgt * bflo(u.x); acc[1] += wgt * bfhi(u.x);
      acc[2] += wgt * bflo(u.y); acc[3] += wgt * bfhi(u.y);
      acc[4] += wgt * bflo(u.z); acc[5] += wgt * bfhi(u.z);
      acc[6] += wgt * bflo(u.w); acc[7] += wgt * bfhi(u.w);
    }
    for (int j0 = 0; j0 < deg; j0 += 8) {
      // 4 pairs = 8 edges; 4 independent 16B loads in flight.
      // OOB indices (>= deg): p0/p1 are 0 on those lanes, sreg = nid (valid addr).
      int e0i = j0 + 0 + grp, e1i = j0 + 2 + grp, e2i = j0 + 4 + grp, e3i = j0 + 6 + grp;
      int sA = __shfl(sreg, e0i), sB = __shfl(sreg, e1i);
      int sC = __shfl(sreg, e2i), sD = __shfl(sreg, e3i);
      float a0A = __shfl(p0, e0i), a1A = __shfl(p1, e0i);
      float a0B = __shfl(p0, e1i), a1B = __shfl(p1, e1i);
      float a0C = __shfl(p0, e2i), a1C = __shfl(p1, e2i);
      float a0D = __shfl(p0, e3i), a1D = __shfl(p1, e3i);
      float gA = h2 ? a1A : a0A;
      float gB = h2 ? a1B : a0B;
      float gC = h2 ? a1C : a0C;
      float gD = h2 ? a1D : a0D;
      uint4 uA = *(const uint4*)(xpw + (size_t)sA * 128 + l32 * 4);
      uint4 uB = *(const uint4*)(xpw + (size_t)sB * 128 + l32 * 4);
      uint4 uC = *(const uint4*)(xpw + (size_t)sC * 128 + l32 * 4);
      uint4 uD = *(const uint4*)(xpw + (size_t)sD * 128 + l32 * 4);
      acc[0] += gA * bflo(uA.x); acc[1] += gA * bfhi(uA.x);
      acc[2] += gA * bflo(uA.y); acc[3] += gA * bfhi(uA.y);
      acc[4] += gA * bflo(uA.z); acc[5] += gA * bfhi(uA.z);
      acc[6] += gA * bflo(uA.w); acc[7] += gA * bfhi(uA.w);
      acc[0] += gB * bflo(uB.x); acc[1] += gB * bfhi(uB.x);
      acc[2] += gB * bflo(uB.y); acc[3] += gB * bfhi(uB.y);
      acc[4] += gB * bflo(uB.z); acc[5] += gB * bfhi(uB.z);
      acc[6] += gB * bflo(uB.w); acc[7] += gB * bfhi(uB.w);
      acc[0] += gC * bflo(uC.x); acc[1] += gC * bfhi(uC.x);
      acc[2] += gC * bflo(uC.y); acc[3] += gC * bfhi(uC.y);
      acc[4] += gC * bflo(uC.z); acc[5] += gC * bfhi(uC.z);
      acc[6] += gC * bflo(uC.w); acc[7] += gC * bfhi(uC.w);
      acc[0] += gD * bflo(uD.x); acc[1] += gD * bfhi(uD.x);
      acc[2] += gD * bflo(uD.y); acc[3] += gD * bfhi(uD.y);
      acc[4] += gD * bflo(uD.z); acc[5] += gD * bfhi(uD.z);
      acc[6] += gD * bflo(uD.w); acc[7] += gD * bfhi(uD.w);
    }
    // merge the two edge-groups
#pragma unroll
    for (int i = 0; i < 8; ++i) acc[i] += __shfl_xor(acc[i], 32);
    if (grp == 0) {
      int c0 = l32 * 8;
      float4 b0 = *(const float4*)(bias + c0);
      float4 b1 = *(const float4*)(bias + c0 + 4);
      float ob[8] = {b0.x, b0.y, b0.z, b0.w, b1.x, b1.y, b1.z, b1.w};
      unsigned short h[8];
#pragma unroll
      for (int i = 0; i < 8; ++i) {
        float v = acc[i] * inv + ob[i];
        v = v > 0.f ? v : __expf(v) - 1.f;
        h[i] = f2bf(v);
      }
      uint4 o;
      o.x = (unsigned)h[0] | ((unsigned)h[1] << 16);
      o.y = (unsigned)h[2] | ((unsigned)h[3] << 16);
      o.z = (unsigned)h[4] | ((unsigned)h[5] << 16);
      o.w = (unsigned)h[6] | ((unsigned)h[7] << 16);
      *(uint4*)(y + (size_t)nid * 256 + c0) = o;
    }
    return;
  }

  // ---- slow path (deg > 64, vanishingly rare): 64-lane x 8B layout ----
  int head = lane >> 5;
  float m0 = e0s, m1 = e1s;
  for (int j = beg + lane; j < end; j += 64) {
    int s = csr[j];
    float as0 = a_s[2 * s], as1 = a_s[2 * s + 1];
    float e0 = as0 + d0; e0 = e0 > 0.f ? e0 : 0.2f * e0;
    float e1 = as1 + d1; e1 = e1 > 0.f ? e1 : 0.2f * e1;
    m0 = fmaxf(m0, e0); m1 = fmaxf(m1, e1);
  }
#pragma unroll
  for (int o = 32; o; o >>= 1) {
    m0 = fmaxf(m0, __shfl_xor(m0, o));
    m1 = fmaxf(m1, __shfl_xor(m1, o));
  }
  float dh = head ? d1 : d0;
  float mh = head ? m1 : m0;
  float ax, ay, az, aw, wsum;
  {
    float e = head ? e1s : e0s;
    float wgt = __expf(e - mh);
    ushort4 u = *(const ushort4*)(xp + (size_t)nid * 256 + lane * 4);
    ax = wgt * bf2f(u.x); ay = wgt * bf2f(u.y); az = wgt * bf2f(u.z); aw = wgt * bf2f(u.w);
    wsum = wgt;
  }
  for (int j = beg; j < end; ++j) {
    int s = csr[j];
    float as = a_s[2 * s + head];
    float e = as + dh; e = e > 0.f ? e : 0.2f * e;
    float wgt = __expf(e - mh);
    ushort4 u = *(const ushort4*)(xp + (size_t)s * 256 + lane * 4);
    ax += wgt * bf2f(u.x); ay += wgt * bf2f(u.y); az += wgt * bf2f(u.z); aw += wgt * bf2f(u.w);
    wsum += wgt;
  }
  float inv = 1.f / wsum;
  float4 b4 = *(const float4*)(bias + lane * 4);
  float o0 = ax * inv + b4.x, o1 = ay * inv + b4.y;
  float o2 = az * inv + b4.z, o3 = aw * inv + b4.w;
  o0 = o0 > 0.f ? o0 : __expf(o0) - 1.f;
  o1 = o1 > 0.f ? o1 : __expf(o1) - 1.f;
  o2 = o2 > 0.f ? o2 : __expf(o2) - 1.f;
  o3 = o3 > 0.f ? o3 : __expf(o3) - 1.f;
  ushort4 yo; yo.x = f2bf(o0); yo.y = f2bf(o1); yo.z = f2bf(o2); yo.w = f2bf(o3);
  *(ushort4*)(y + (size_t)nid * 256 + lane * 4) = yo;
}

// ---------------- GEMM2 fused: t = y@mlp_w + b, pooled into S[g][c], Q[c] ----------------
__global__ void __launch_bounds__(256) mlp_gemm_kernel(
    const unsigned short* __restrict__ y,
    const unsigned short* __restrict__ mwth, const unsigned short* __restrict__ mwtl,
    const float* __restrict__ mlp_b, const int* __restrict__ batch,
    float* __restrict__ S, float* __restrict__ Q) {
  __shared__ unsigned short Ahs[4 * 64 * 8];
  __shared__ unsigned short Bh[4 * 128 * 8], Bl[4 * 128 * 8];
  __shared__ float Sloc[128], Qloc[128];
  int tid = threadIdx.x;
  int w = tid >> 6, lane = tid & 63;
  int m = lane & 15, quad = lane >> 4;
  int r0 = blockIdx.x * 64;
  if (tid < 128) { Sloc[tid] = 0.f; Qloc[tid] = 0.f; }

  f32x4 acc[8];
#pragma unroll
  for (int c = 0; c < 8; ++c) acc[c] = (f32x4){0.f, 0.f, 0.f, 0.f};

  for (int kc = 0; kc < 8; ++kc) {
    int k0 = kc * 32;
    gld_lds16(y + (size_t)(r0 + lane) * 256 + k0 + w * 8, Ahs + w * 512);
#pragma unroll
    for (int i = 0; i < 2; ++i) {
      int n = i * 64 + lane;
      gld_lds16(mwth + (size_t)n * 256 + k0 + w * 8, Bh + w * 1024 + i * 512);
      gld_lds16(mwtl + (size_t)n * 256 + k0 + w * 8, Bl + w * 1024 + i * 512);
    }
    __syncthreads();
    bf16x8 ah = *(const bf16x8*)(Ahs + quad * 512 + (w * 16 + m) * 8);
#pragma unroll
    for (int c = 0; c < 8; ++c) {
      bf16x8 bh = *(const bf16x8*)(Bh + quad * 1024 + (c * 16 + m) * 8);
      bf16x8 bl = *(const bf16x8*)(Bl + quad * 1024 + (c * 16 + m) * 8);
      acc[c] = __builtin_amdgcn_mfma_f32_16x16x32_bf16(ah, bh, acc[c], 0, 0, 0);
      acc[c] = __builtin_amdgcn_mfma_f32_16x16x32_bf16(ah, bl, acc[c], 0, 0, 0);
    }
    __syncthreads();
  }
  int rowb = r0 + w * 16 + quad * 4;
  int gfirst = batch[r0];
  int glast = batch[min(r0 + 63, N_NODES - 1)];
  bool uni = (gfirst == glast);
  bool valid[4]; int gg[4];
#pragma unroll
  for (int r = 0; r < 4; ++r) {
    int row = rowb + r;
    valid[r] = row < N_NODES;
    gg[r] = (!uni && valid[r]) ? batch[row] : gfirst;
  }
#pragma unroll
  for (int c = 0; c < 8; ++c) {
    int col = c * 16 + m;
    float bv = mlp_b[col];
    float sc = 0.f, qc = 0.f;
#pragma unroll
    for (int r = 0; r < 4; ++r) {
      if (valid[r]) {
        float v = acc[c][r] + bv;
        qc += v * v;
        if (uni) sc += v;
        else atomicAdd(&S[gg[r] * 128 + col], v);
      }
    }
    qc += __shfl_xor(qc, 16); qc += __shfl_xor(qc, 32);
    sc += __shfl_xor(sc, 16); sc += __shfl_xor(sc, 32);
    if (quad == 0) {
      atomicAdd(&Qloc[col], qc);
      if (uni) atomicAdd(&Sloc[col], sc);
    }
  }
  __syncthreads();
  if (tid < 128) {
    atomicAdd(&Q[tid], Qloc[tid]);
    if (uni) atomicAdd(&S[gfirst * 128 + tid], Sloc[tid]);
  }
}

// hp[g][c] = bn0_g*rsq*(S - cnt*mu) + cnt*bn0_b
__global__ void bn0hp_kernel(const float* __restrict__ S, const float* __restrict__ Q,
                             const int* __restrict__ cnt, const float* __restrict__ g0,
                             const float* __restrict__ b0, float* __restrict__ hp) {
  int c = threadIdx.x;            // 128
  float sum = 0.f;
  for (int g = 0; g < NGRAPH; ++g) sum += S[g * 128 + c];
  float mu = sum / (float)N_NODES;
  float var = Q[c] / (float)N_NODES - mu * mu;
  float gam = g0[c] * rsqrtf(var + BN_EPS);
  float bet = b0[c];
  for (int g = 0; g < NGRAPH; ++g) {
    float k = (float)cnt[g];
    hp[g * 128 + c] = gam * (S[g * 128 + c] - k * mu) + k * bet;
  }
}

// ---------------- FC head ----------------
__global__ void fc1_kernel(const float* __restrict__ hp, const float* __restrict__ w,
                           const float* __restrict__ b, const float* __restrict__ bng,
                           const float* __restrict__ bnb, float* __restrict__ z1) {
  int wv = threadIdx.x >> 6, lane = threadIdx.x & 63;
  int j = blockIdx.x * 4 + wv;    // 0..511
  float acc = b[j];
  for (int c = 0; c < 128; ++c) acc += hp[lane * 128 + c] * w[c * 512 + j];
  float s1 = acc, s2 = acc * acc;
#pragma unroll
  for (int o = 32; o; o >>= 1) { s1 += __shfl_xor(s1, o); s2 += __shfl_xor(s2, o); }
  float mu = s1 * (1.f / 64.f), var = s2 * (1.f / 64.f) - mu * mu;
  float z = bng[j] * (acc - mu) * rsqrtf(var + BN_EPS) + bnb[j];
  z1[lane * 512 + j] = fmaxf(z, 0.f);
}

__global__ void fc2_kernel(const float* __restrict__ z1, const float* __restrict__ w,
                           const float* __restrict__ b, const float* __restrict__ bng,
                           const float* __restrict__ bnb, float* __restrict__ z2) {
  int wv = threadIdx.x >> 6, lane = threadIdx.x & 63;
  int j = blockIdx.x * 4 + wv;    // 0..255
  float acc = b[j];
  for (int c = 0; c < 512; ++c) acc += z1[lane * 512 + c] * w[c * 256 + j];
  float s1 = acc, s2 = acc * acc;
#pragma unroll
  for (int o = 32; o; o >>= 1) { s1 += __shfl_xor(s1, o); s2 += __shfl_xor(s2, o); }
  float mu = s1 * (1.f / 64.f), var = s2 * (1.f / 64.f) - mu * mu;
  float z = bng[j] * (acc - mu) * rsqrtf(var + BN_EPS) + bnb[j];
  z2[lane * 256 + j] = fmaxf(z, 0.f);
}

__global__ void fc3_kernel(const float* __restrict__ z2, const float* __restrict__ w,
                           const float* __restrict__ b, const float* __restrict__ bng,
                           const float* __restrict__ bnb, float* __restrict__ out) {
  int lane = threadIdx.x;         // 64
  float acc = b[0];
  for (int c = 0; c < 256; ++c) acc += z2[lane * 256 + c] * w[c];
  float s1 = acc, s2 = acc * acc;
#pragma unroll
  for (int o = 32; o; o >>= 1) { s1 += __shfl_xor(s1, o); s2 += __shfl_xor(s2, o); }
  float mu = s1 * (1.f / 64.f), var = s2 * (1.f / 64.f) - mu * mu;
  out[lane] = bng[0] * (acc - mu) * rsqrtf(var + BN_EPS) + bnb[0];
}

extern "C" void kernel_launch(void* const* d_in, const int* in_sizes, int n_in,
                              void* d_out, int out_size, void* d_ws, size_t ws_size,
                              hipStream_t stream) {
  const float* x     = (const float*)d_in[0];
  const float* gat_w = (const float*)d_in[1];
  const float* a_src = (const float*)d_in[2];
  const float* a_dst = (const float*)d_in[3];
  const float* gbias = (const float*)d_in[4];
  const float* mlp_w = (const float*)d_in[5];
  const float* mlp_b = (const float*)d_in[6];
  const float* bn0g  = (const float*)d_in[7];
  const float* bn0b  = (const float*)d_in[8];
  const float* fc1w  = (const float*)d_in[9];
  const float* fc1b  = (const float*)d_in[10];
  const float* bn1g  = (const float*)d_in[11];
  const float* bn1b  = (const float*)d_in[12];
  const float* fc2w  = (const float*)d_in[13];
  const float* fc2b  = (const float*)d_in[14];
  const float* bn2g  = (const float*)d_in[15];
  const float* bn2b  = (const float*)d_in[16];
  const float* fc3w  = (const float*)d_in[17];
  const float* fc3b  = (const float*)d_in[18];
  const float* bn3g  = (const float*)d_in[19];
  const float* bn3b  = (const float*)d_in[20];
  const int* eidx    = (const int*)d_in[21];
  const int* batch   = (const int*)d_in[22];
  float* out = (float*)d_out;

  char* base = (char*)d_ws;
  size_t off = 0;
  auto take = [&](size_t bytes) -> char* {
    char* p = base + off;
    off += (bytes + 255) & ~(size_t)255;
    return p;
  };
  unsigned short* xp   = (unsigned short*)take((size_t)N_NODES * 256 * 2);
  unsigned short* ybf  = (unsigned short*)take((size_t)30016 * 256 * 2);
  unsigned short* wth  = (unsigned short*)take(448 * 256 * 2);
  unsigned short* wtl  = (unsigned short*)take(448 * 256 * 2);
  unsigned short* mwth = (unsigned short*)take(128 * 256 * 2);
  unsigned short* mwtl = (unsigned short*)take(128 * 256 * 2);
  float* a_s = (float*)take((size_t)N_NODES * 2 * 4);
  float* a_d = (float*)take((size_t)N_NODES * 2 * 4);
  int* deg   = (int*)take((size_t)N_NODES * 4);
  int* offs  = (int*)take((size_t)(N_NODES + 1) * 4);
  int* cur   = (int*)take((size_t)N_NODES * 4);
  int* csr   = (int*)take((size_t)N_EDGES * 4);
  float* S   = (float*)take(NGRAPH * 128 * 4);
  float* Q   = (float*)take(128 * 4);
  int* cnt   = (int*)take(NGRAPH * 4);
  float* hp  = (float*)take(NGRAPH * 128 * 4);
  float* z1  = (float*)take(NGRAPH * 512 * 4);
  float* z2  = (float*)take(NGRAPH * 256 * 4);

  hipMemsetAsync(deg, 0, (size_t)N_NODES * 4, stream);
  hipMemsetAsync(S, 0, (size_t)(NGRAPH * 128 * 4 + 512), stream);

  castw_cnt_kernel<<<577, 256, 0, stream>>>(gat_w, mlp_w, wth, wtl, mwth, mwtl, batch, cnt);
  hist_kernel<<<938, 256, 0, stream>>>(eidx, deg);
  scan_kernel<<<1, 1024, 0, stream>>>(deg, offs, cur, N_NODES);
  scatter_kernel<<<938, 256, 0, stream>>>(eidx, cur, csr);
  gat_gemm_kernel<<<NB_GEMM, 256, 0, stream>>>(x, wth, wtl, a_src, a_dst, xp, a_s, a_d);
  attn_kernel<<<7500, 256, 0, stream>>>(xp, a_s, a_d, offs, csr, gbias, ybf);
  mlp_gemm_kernel<<<NB_GEMM, 256, 0, stream>>>(ybf, mwth, mwtl, mlp_b, batch, S, Q);
  bn0hp_kernel<<<1, 128, 0, stream>>>(S, Q, cnt, bn0g, bn0b, hp);
  fc1_kernel<<<128, 256, 0, stream>>>(hp, fc1w, fc1b, bn1g, bn1b, z1);
  fc2_kernel<<<64, 256, 0, stream>>>(z1, fc2w, fc2b, bn2g, bn2b, z2);
  fc3_kernel<<<1, 64, 0, stream>>>(z2, fc3w, fc3b, bn3g, bn3b, out);

  (void)in_sizes; (void)n_in; (void)out_size; (void)ws_size;
}